// Round 15
// baseline (260.981 us; speedup 1.0000x reference)
//
#include <hip/hip_runtime.h>

#define NTOK 65536
#define DIM 256
#define KC 1024
#define EPS 0.08f

typedef __attribute__((ext_vector_type(8))) _Float16 f16x8;
typedef __attribute__((ext_vector_type(8))) unsigned short u16x8;
typedef __attribute__((ext_vector_type(4))) float f32x4;

static __device__ __forceinline__ unsigned short f16bits(float f) {
  _Float16 h = (_Float16)f;
  return __builtin_bit_cast(unsigned short, h);
}
static __device__ __forceinline__ void gload16(const void* g, void* l) {
  __builtin_amdgcn_global_load_lds(
      (const __attribute__((address_space(1))) unsigned int*)g,
      (__attribute__((address_space(3))) unsigned int*)l, 16, 0, 0);
}

// ---- e: fp32 -> fp16 FRAGMENT-MAJOR global image + esq; zero scalars ----
__global__ __launch_bounds__(256) void vq_prep_e(const float* __restrict__ e,
                                                 unsigned short* __restrict__ eg,
                                                 float* __restrict__ esq,
                                                 int* __restrict__ hist,
                                                 int* __restrict__ fixCount) {
  const int gid = blockIdx.x * 256 + threadIdx.x;
  const int t = gid >> 5;
  const int o = gid & 31;
  const float4 v0 = *reinterpret_cast<const float4*>(&e[t * DIM + o * 8]);
  const float4 v1 = *reinterpret_cast<const float4*>(&e[t * DIM + o * 8 + 4]);
  u16x8 u;
  u[0] = f16bits(v0.x); u[1] = f16bits(v0.y); u[2] = f16bits(v0.z); u[3] = f16bits(v0.w);
  u[4] = f16bits(v1.x); u[5] = f16bits(v1.y); u[6] = f16bits(v1.z); u[7] = f16bits(v1.w);
  const int ctk = t >> 6, njj = (t >> 4) & 3, col = t & 15;
  const int s = o >> 2, kq = o & 3;
  char* dst = (char*)eg + ((ctk * 32 + s * 4 + njj) << 10) + ((kq * 16 + col) << 4);
  *reinterpret_cast<u16x8*>(dst) = u;
  float p = v0.x * v0.x + v0.y * v0.y + v0.z * v0.z + v0.w * v0.w +
            v1.x * v1.x + v1.y * v1.y + v1.z * v1.z + v1.w * v1.w;
#pragma unroll
  for (int m = 16; m > 0; m >>= 1) p += __shfl_xor(p, m, 64);
  if (o == 0) esq[t] = p;
  if (blockIdx.x < 4) hist[blockIdx.x * 256 + threadIdx.x] = 0;
  if (gid == 0) *fixCount = 0;
}

// ---- templated argmin: V=0 FULL (real), V=1 NOCOMPUTE, V=2 NOSTAGE ----
template <int V>
__global__ __launch_bounds__(128, 2) void vq_argmin_t(
    const float* __restrict__ x, const unsigned short* __restrict__ eg,
    const float* __restrict__ esq, const float* __restrict__ e,
    float* __restrict__ outIdxF, float* __restrict__ outQ,
    float* __restrict__ bestDist, float* __restrict__ xsq,
    int* __restrict__ hist, int* __restrict__ fixCount,
    unsigned int* __restrict__ fixList, float* __restrict__ dummy) {
  __shared__ char esb[3 * 8192];
  __shared__ float es_sq[KC];

  const int tid = threadIdx.x;
  const int lane = tid & 63, w = tid >> 6;
  const int col = lane & 15, kq = lane >> 4;
  const int tw = blockIdx.x * 64 + w * 32;

  {
    const float4* s4 = reinterpret_cast<const float4*>(esq);
    float4* d4 = reinterpret_cast<float4*>(es_sq);
    d4[tid * 2] = s4[tid * 2];
    d4[tid * 2 + 1] = s4[tid * 2 + 1];
  }

  f16x8 a[2][8];
  float sqm[2] = {0.f, 0.f};
#pragma unroll
  for (int mi = 0; mi < 2; ++mi) {
#pragma unroll
    for (int s = 0; s < 8; ++s) {
      const float* xp = &x[(tw + mi * 16 + col) * DIM + s * 32 + kq * 8];
      const float4 v0 = *reinterpret_cast<const float4*>(xp);
      const float4 v1 = *reinterpret_cast<const float4*>(xp + 4);
      a[mi][s][0] = (_Float16)v0.x; a[mi][s][1] = (_Float16)v0.y;
      a[mi][s][2] = (_Float16)v0.z; a[mi][s][3] = (_Float16)v0.w;
      a[mi][s][4] = (_Float16)v1.x; a[mi][s][5] = (_Float16)v1.y;
      a[mi][s][6] = (_Float16)v1.z; a[mi][s][7] = (_Float16)v1.w;
      sqm[mi] += v0.x * v0.x + v0.y * v0.y + v0.z * v0.z + v0.w * v0.w +
                 v1.x * v1.x + v1.y * v1.y + v1.z * v1.z + v1.w * v1.w;
    }
  }
#pragma unroll
  for (int mi = 0; mi < 2; ++mi) {
    sqm[mi] += __shfl_xor(sqm[mi], 16, 64);
    sqm[mi] += __shfl_xor(sqm[mi], 32, 64);
  }
  if (V == 0 && lane < 16) {
    xsq[tw + lane] = sqm[0];
    xsq[tw + 16 + lane] = sqm[1];
  }

  auto STAGE = [&](int q, int b) {
#pragma unroll
    for (int i = 0; i < 4; ++i)
      gload16((const char*)eg + q * 8192 + w * 4096 + i * 1024 + lane * 16,
              esb + b * 8192 + w * 4096 + i * 1024);
  };

  float v1_[2][4], v2_[2][4], v3_[2][4];
  int i1_[2][4], i2_[2][4];
#pragma unroll
  for (int mi = 0; mi < 2; ++mi)
#pragma unroll
    for (int r = 0; r < 4; ++r) {
      v1_[mi][r] = 3.4e38f; v2_[mi][r] = 3.4e38f; v3_[mi][r] = 3.4e38f;
      i1_[mi][r] = 0; i2_[mi][r] = 0;
    }

  STAGE(0, 0);
  if (V == 2) {  // one-time stage; loop then has no barriers at all
    asm volatile("s_waitcnt vmcnt(0)" ::: "memory");
    __builtin_amdgcn_s_barrier();
    asm volatile("" ::: "memory");
  }

  f32x4 acc[2][4];
  for (int ctk = 0; ctk < 16; ++ctk) {
    if (V != 1) {
#pragma unroll
      for (int mi = 0; mi < 2; ++mi)
#pragma unroll
        for (int nj = 0; nj < 4; ++nj) acc[mi][nj] = (f32x4){0.f, 0.f, 0.f, 0.f};
    }

#pragma unroll
    for (int ks2 = 0; ks2 < 4; ++ks2) {
      const int q = ctk * 4 + ks2;
      if (V != 2) {
        if (q < 63) {
          STAGE(q + 1, (q + 1) % 3);
          asm volatile("s_waitcnt vmcnt(4)" ::: "memory");
        } else {
          asm volatile("s_waitcnt vmcnt(0)" ::: "memory");
        }
        __builtin_amdgcn_s_barrier();
        asm volatile("" ::: "memory");
      }

      const char* bb = (V == 2) ? esb : esb + (q % 3) * 8192;
#pragma unroll
      for (int h = 0; h < 2; ++h) {
        f16x8 bfr[4];
#pragma unroll
        for (int njj = 0; njj < 4; ++njj)
          bfr[njj] = *reinterpret_cast<const f16x8*>(
              bb + (h * 4 + njj) * 1024 + lane * 16);
        if (V == 1) {
          asm volatile("" ::"v"(bfr[0]), "v"(bfr[1]), "v"(bfr[2]), "v"(bfr[3]));
        } else {
          const int sg = ks2 * 2 + h;
#pragma unroll
          for (int mi = 0; mi < 2; ++mi)
#pragma unroll
            for (int njj = 0; njj < 4; ++njj)
              acc[mi][njj] = __builtin_amdgcn_mfma_f32_16x16x32_f16(
                  a[mi][sg], bfr[njj], acc[mi][njj], 0, 0, 0);
        }
      }
    }

    if (V != 1) {
#pragma unroll
      for (int njj = 0; njj < 4; ++njj) {
        const int code = ctk * 64 + njj * 16 + col;
        const float sqv = es_sq[code];
#pragma unroll
        for (int mi = 0; mi < 2; ++mi)
#pragma unroll
          for (int r = 0; r < 4; ++r) {
            const float d = fmaf(-2.f, acc[mi][njj][r], sqv);
            if (d < v1_[mi][r]) {
              v3_[mi][r] = v2_[mi][r]; v2_[mi][r] = v1_[mi][r];
              i2_[mi][r] = i1_[mi][r];
              v1_[mi][r] = d; i1_[mi][r] = code;
            } else if (d < v2_[mi][r]) {
              v3_[mi][r] = v2_[mi][r]; v2_[mi][r] = d; i2_[mi][r] = code;
            } else if (d < v3_[mi][r]) {
              v3_[mi][r] = d;
            }
          }
      }
    }
  }

  if (V == 1) {
    // keep staging results observable; negligible traffic
    if (lane == 0) dummy[blockIdx.x * 2 + w] = sqm[0];
    return;
  }

  // cross-lane top-3 merge
#pragma unroll
  for (int mi = 0; mi < 2; ++mi)
#pragma unroll
    for (int r = 0; r < 4; ++r) {
      float mv1 = v1_[mi][r], mv2 = v2_[mi][r], mv3 = v3_[mi][r];
      int mi1 = i1_[mi][r], mi2 = i2_[mi][r];
#pragma unroll
      for (int m = 1; m <= 8; m <<= 1) {
        const float ov1 = __shfl_xor(mv1, m, 64);
        const float ov2 = __shfl_xor(mv2, m, 64);
        const float ov3 = __shfl_xor(mv3, m, 64);
        const int oi1 = __shfl_xor(mi1, m, 64);
        const int oi2 = __shfl_xor(mi2, m, 64);
        const bool oW = (ov1 < mv1) || (ov1 == mv1 && oi1 < mi1);
        const float wv1 = oW ? ov1 : mv1, wv2 = oW ? ov2 : mv2, wv3 = oW ? ov3 : mv3;
        const int wi1 = oW ? oi1 : mi1, wi2 = oW ? oi2 : mi2;
        const float lv1 = oW ? mv1 : ov1, lv2 = oW ? mv2 : ov2;
        const int li1 = oW ? mi1 : oi1;
        const bool w2 = (wv2 < lv1) || (wv2 == lv1 && wi2 < li1);
        mv1 = wv1; mi1 = wi1;
        mv2 = w2 ? wv2 : lv1;
        mi2 = w2 ? wi2 : li1;
        mv3 = w2 ? fminf(wv3, lv1) : fminf(wv2, lv2);
      }
      if (col == 0) {
        if (V == 0) {
          const int t = tw + mi * 16 + kq * 4 + r;
          outIdxF[t] = (float)mi1;
          bestDist[t] = mv1;
          atomicAdd(&hist[mi1], 1);
          if (mv2 - mv1 < EPS) {
            const unsigned full = (mv3 - mv1 < EPS) ? 0x80000000u : 0u;
            const int pp = atomicAdd(fixCount, 1);
            fixList[pp * 2] = (unsigned)t | full;
            fixList[pp * 2 + 1] = (unsigned)mi2;
          }
        } else {
          dummy[blockIdx.x * 64 + w * 32 + mi * 16 + kq * 4 + r] =
              mv1 + mv2 + mv3 + (float)mi1 + (float)mi2;
        }
      }
      i1_[mi][r] = mi1;
    }

  if (V == 0) {
#pragma unroll
    for (int i = 0; i < 32; ++i) {
      const int id = __shfl(i1_[i >> 4][i & 3], ((i >> 2) & 3) * 16, 64);
      const float4 q = reinterpret_cast<const float4*>(&e[id * DIM])[lane];
      reinterpret_cast<float4*>(&outQ[(tw + i) * DIM])[lane] = q;
    }
  }
}

// ---- fixup ----
__global__ __launch_bounds__(256) void vq_fixup(
    const float* __restrict__ x, const float* __restrict__ e,
    const int* __restrict__ fixCount, const unsigned int* __restrict__ fixList,
    float* __restrict__ outIdxF, float* __restrict__ outQ,
    float* __restrict__ bestDist, int* __restrict__ hist) {
  const int n = *fixCount;
  const int tid = threadIdx.x;
  __shared__ float xrow[256];
  __shared__ float rv[4];
  __shared__ int ri[4];
  __shared__ int sOld, sFi;
  for (int it = blockIdx.x; it < n; it += gridDim.x) {
    const unsigned e0 = fixList[it * 2];
    const int t = (int)(e0 & 0x3FFFFFFFu);
    const bool full = (e0 >> 31) != 0u;
    if (!full) {
      if (tid < 64) {
        const int i1 = (int)outIdxF[t];
        const int i2 = (int)fixList[it * 2 + 1];
        const float4 xv = reinterpret_cast<const float4*>(&x[t * DIM])[tid];
        const float4 e1 = reinterpret_cast<const float4*>(&e[i1 * DIM])[tid];
        const float4 e2 = reinterpret_cast<const float4*>(&e[i2 * DIM])[tid];
        float d1 = (xv.x - e1.x) * (xv.x - e1.x) + (xv.y - e1.y) * (xv.y - e1.y) +
                   (xv.z - e1.z) * (xv.z - e1.z) + (xv.w - e1.w) * (xv.w - e1.w);
        float d2 = (xv.x - e2.x) * (xv.x - e2.x) + (xv.y - e2.y) * (xv.y - e2.y) +
                   (xv.z - e2.z) * (xv.z - e2.z) + (xv.w - e2.w) * (xv.w - e2.w);
#pragma unroll
        for (int m = 32; m > 0; m >>= 1) {
          d1 += __shfl_xor(d1, m, 64);
          d2 += __shfl_xor(d2, m, 64);
        }
        const bool swap2 = (d2 < d1) || (d2 == d1 && i2 < i1);
        const int wIdx = swap2 ? i2 : i1;
        const float wD = swap2 ? d2 : d1;
        if (tid == 0) {
          bestDist[t] = wD;
          if (wIdx != i1) {
            atomicSub(&hist[i1], 1);
            atomicAdd(&hist[wIdx], 1);
            outIdxF[t] = (float)wIdx;
          }
        }
        if (swap2) {
          const float4 q = reinterpret_cast<const float4*>(&e[wIdx * DIM])[tid];
          reinterpret_cast<float4*>(&outQ[t * DIM])[tid] = q;
        }
      }
    } else {
      __syncthreads();
      if (tid < 64) ((float4*)xrow)[tid] = ((const float4*)&x[t * DIM])[tid];
      __syncthreads();
      float bv = 3.4e38f; int bi = 0;
      for (int c = tid; c < KC; c += 256) {
        float s = 0.f;
#pragma unroll
        for (int d = 0; d < DIM; d += 4) {
          const float4 ev = *(const float4*)&e[c * DIM + d];
          const float d0 = xrow[d] - ev.x, d1 = xrow[d + 1] - ev.y;
          const float d2 = xrow[d + 2] - ev.z, d3 = xrow[d + 3] - ev.w;
          s += d0 * d0 + d1 * d1 + d2 * d2 + d3 * d3;
        }
        if (s < bv) { bv = s; bi = c; }
      }
#pragma unroll
      for (int m = 1; m <= 32; m <<= 1) {
        const float ob = __shfl_xor(bv, m, 64);
        const int oi = __shfl_xor(bi, m, 64);
        if (ob < bv || (ob == bv && oi < bi)) { bv = ob; bi = oi; }
      }
      const int lane = tid & 63, wv = tid >> 6;
      if (lane == 0) { rv[wv] = bv; ri[wv] = bi; }
      __syncthreads();
      if (tid == 0) {
        float fb = rv[0]; int fi = ri[0];
        for (int k = 1; k < 4; ++k)
          if (rv[k] < fb || (rv[k] == fb && ri[k] < fi)) { fb = rv[k]; fi = ri[k]; }
        sOld = (int)outIdxF[t];
        sFi = fi;
        bestDist[t] = fb;
        if (fi != sOld) {
          atomicSub(&hist[sOld], 1);
          atomicAdd(&hist[fi], 1);
          outIdxF[t] = (float)fi;
        }
      }
      __syncthreads();
      if (sFi != sOld) outQ[t * DIM + tid] = e[sFi * DIM + tid];
      __syncthreads();
    }
  }
}

// ---- final scalars ----
__global__ __launch_bounds__(1024) void vq_final(
    const int* __restrict__ hist, const float* __restrict__ xsq,
    const float* __restrict__ bestDist, float* __restrict__ outLoss,
    float* __restrict__ outPerp) {
  const int tid = threadIdx.x;
  float ls = 0.f;
  for (int i = 0; i < 64; ++i) {
    const int t = tid + i * 1024;
    ls += xsq[t] + bestDist[t];
  }
  const float p = (float)hist[tid] * (1.f / 65536.f);
  float ent = p * logf(p + 1e-10f);
#pragma unroll
  for (int o = 32; o > 0; o >>= 1) {
    ls += __shfl_down(ls, o, 64);
    ent += __shfl_down(ent, o, 64);
  }
  __shared__ float lbuf[16], ebuf[16];
  const int lane = tid & 63, wv = tid >> 6;
  if (lane == 0) { lbuf[wv] = ls; ebuf[wv] = ent; }
  __syncthreads();
  if (tid == 0) {
    float L = 0.f, E = 0.f;
    for (int i = 0; i < 16; ++i) { L += lbuf[i]; E += ebuf[i]; }
    *outLoss = 0.25f * (L / 16777216.f);
    *outPerp = expf(-E);
  }
}

extern "C" void kernel_launch(void* const* d_in, const int* in_sizes, int n_in,
                              void* d_out, int out_size, void* d_ws, size_t ws_size,
                              hipStream_t stream) {
  const float* x = (const float*)d_in[0];
  const float* e = (const float*)d_in[1];
  float* out = (float*)d_out;
  float* outQ = out;
  float* outLoss = out + 16777216;
  float* outPerp = out + 16777217;
  float* outIdxF = out + 16777218;

  char* ws = (char*)d_ws;
  int*   hist     = (int*)ws;                     // 4 KB
  float* esq      = (float*)(ws + 4096);          // 4 KB
  float* xsq      = (float*)(ws + 8192);          // 256 KB
  float* bestDist = (float*)(ws + 270336);        // 256 KB
  int*   fixCount = (int*)(ws + 532480);          // 16 B
  unsigned int* fixList = (unsigned int*)(ws + 532496);  // 512 KB
  unsigned short* e_f16 = (unsigned short*)(ws + 1056784);  // 512 KB
  float* dummy    = (float*)(ws + 1581072);       // 256 KB (ablation sink)

  vq_prep_e<<<128, 256, 0, stream>>>(e, e_f16, esq, hist, fixCount);
  // control (real output)
  vq_argmin_t<0><<<NTOK / 64, 128, 0, stream>>>(x, e_f16, esq, e, outIdxF, outQ,
                                                bestDist, xsq, hist, fixCount,
                                                fixList, dummy);
  // ablation: memory/barrier chain only
  vq_argmin_t<1><<<NTOK / 64, 128, 0, stream>>>(x, e_f16, esq, e, outIdxF, outQ,
                                                bestDist, xsq, hist, fixCount,
                                                fixList, dummy);
  // ablation: compute side only (no per-chunk staging/barriers)
  vq_argmin_t<2><<<NTOK / 64, 128, 0, stream>>>(x, e_f16, esq, e, outIdxF, outQ,
                                                bestDist, xsq, hist, fixCount,
                                                fixList, dummy);
  vq_fixup<<<256, 256, 0, stream>>>(x, e, fixCount, fixList, outIdxF, outQ,
                                    bestDist, hist);
  vq_final<<<1, 1024, 0, stream>>>(hist, xsq, bestDist, outLoss, outPerp);
}

// Round 16
// 224.426 us; speedup vs baseline: 1.1629x; 1.1629x over previous
//
#include <hip/hip_runtime.h>

#define NTOK 65536
#define DIM 256
#define KC 1024
#define EPS 0.08f

typedef __attribute__((ext_vector_type(8))) _Float16 f16x8;
typedef __attribute__((ext_vector_type(8))) unsigned short u16x8;
typedef __attribute__((ext_vector_type(4))) float f32x4;

static __device__ __forceinline__ unsigned short f16bits(float f) {
  _Float16 h = (_Float16)f;
  return __builtin_bit_cast(unsigned short, h);
}
static __device__ __forceinline__ void gload16(const void* g, void* l) {
  __builtin_amdgcn_global_load_lds(
      (const __attribute__((address_space(1))) unsigned int*)g,
      (__attribute__((address_space(3))) unsigned int*)l, 16, 0, 0);
}
#define VWAIT(n) asm volatile("s_waitcnt vmcnt(" #n ")" ::: "memory")
#define MEMFENCE() asm volatile("" ::: "memory")

// ---- e: fp32 -> fp16 FRAGMENT-MAJOR global image + esq; zero scalars ----
__global__ __launch_bounds__(256) void vq_prep_e(const float* __restrict__ e,
                                                 unsigned short* __restrict__ eg,
                                                 float* __restrict__ esq,
                                                 int* __restrict__ hist,
                                                 int* __restrict__ fixCount) {
  const int gid = blockIdx.x * 256 + threadIdx.x;
  const int t = gid >> 5;
  const int o = gid & 31;
  const float4 v0 = *reinterpret_cast<const float4*>(&e[t * DIM + o * 8]);
  const float4 v1 = *reinterpret_cast<const float4*>(&e[t * DIM + o * 8 + 4]);
  u16x8 u;
  u[0] = f16bits(v0.x); u[1] = f16bits(v0.y); u[2] = f16bits(v0.z); u[3] = f16bits(v0.w);
  u[4] = f16bits(v1.x); u[5] = f16bits(v1.y); u[6] = f16bits(v1.z); u[7] = f16bits(v1.w);
  const int ctk = t >> 6, njj = (t >> 4) & 3, col = t & 15;
  const int s = o >> 2, kq = o & 3;
  char* dst = (char*)eg + ((ctk * 32 + s * 4 + njj) << 10) + ((kq * 16 + col) << 4);
  *reinterpret_cast<u16x8*>(dst) = u;
  float p = v0.x * v0.x + v0.y * v0.y + v0.z * v0.z + v0.w * v0.w +
            v1.x * v1.x + v1.y * v1.y + v1.z * v1.z + v1.w * v1.w;
#pragma unroll
  for (int m = 16; m > 0; m >>= 1) p += __shfl_xor(p, m, 64);
  if (o == 0) esq[t] = p;
  if (blockIdx.x < 4) hist[blockIdx.x * 256 + threadIdx.x] = 0;
  if (gid == 0) *fixCount = 0;
}

// ---- 64-token / 2-wave blocks; DEEP pipeline: 4 chunks in flight ----
// 6-buffer LDS rotation, STAGE(q+4) + vmcnt(16) steady state (chunk q
// guaranteed landed; 3 chunk-times of lookahead > L2 latency).
__global__ __launch_bounds__(128, 2) void vq_argmin(
    const float* __restrict__ x, const unsigned short* __restrict__ eg,
    const float* __restrict__ esq, const float* __restrict__ e,
    float* __restrict__ outIdxF, float* __restrict__ outQ,
    float* __restrict__ bestDist, float* __restrict__ xsq,
    int* __restrict__ hist, int* __restrict__ fixCount,
    unsigned int* __restrict__ fixList) {
  __shared__ char esb[6 * 8192];   // 48 KB: 6 rotating 8-KB e buffers
  __shared__ float es_sq[KC];      // 4 KB: esq copy (ds_read, no vmcnt)

  const int tid = threadIdx.x;
  const int lane = tid & 63, w = tid >> 6;
  const int col = lane & 15, kq = lane >> 4;
  const int tw = blockIdx.x * 64 + w * 32;

  {
    const float4* s4 = reinterpret_cast<const float4*>(esq);
    float4* d4 = reinterpret_cast<float4*>(es_sq);
    d4[tid * 2] = s4[tid * 2];
    d4[tid * 2 + 1] = s4[tid * 2 + 1];
  }

  // prologue: x -> A-fragments; token tw + mi*16 + col, k = s*32+kq*8+j
  f16x8 a[2][8];
  float sqm[2] = {0.f, 0.f};
#pragma unroll
  for (int mi = 0; mi < 2; ++mi) {
#pragma unroll
    for (int s = 0; s < 8; ++s) {
      const float* xp = &x[(tw + mi * 16 + col) * DIM + s * 32 + kq * 8];
      const float4 v0 = *reinterpret_cast<const float4*>(xp);
      const float4 v1 = *reinterpret_cast<const float4*>(xp + 4);
      a[mi][s][0] = (_Float16)v0.x; a[mi][s][1] = (_Float16)v0.y;
      a[mi][s][2] = (_Float16)v0.z; a[mi][s][3] = (_Float16)v0.w;
      a[mi][s][4] = (_Float16)v1.x; a[mi][s][5] = (_Float16)v1.y;
      a[mi][s][6] = (_Float16)v1.z; a[mi][s][7] = (_Float16)v1.w;
      sqm[mi] += v0.x * v0.x + v0.y * v0.y + v0.z * v0.z + v0.w * v0.w +
                 v1.x * v1.x + v1.y * v1.y + v1.z * v1.z + v1.w * v1.w;
    }
  }
#pragma unroll
  for (int mi = 0; mi < 2; ++mi) {
    sqm[mi] += __shfl_xor(sqm[mi], 16, 64);
    sqm[mi] += __shfl_xor(sqm[mi], 32, 64);
  }
  if (lane < 16) {
    xsq[tw + lane] = sqm[0];
    xsq[tw + 16 + lane] = sqm[1];
  }

  // stage 8-KB chunk q into buf b; this wave stages its own 4-KB half.
  auto STAGE = [&](int q, int b) {
#pragma unroll
    for (int i = 0; i < 4; ++i)
      gload16((const char*)eg + q * 8192 + w * 4096 + i * 1024 + lane * 16,
              esb + b * 8192 + w * 4096 + i * 1024);
  };

  float v1_[2][4], v2_[2][4], v3_[2][4];
  int i1_[2][4], i2_[2][4];
#pragma unroll
  for (int mi = 0; mi < 2; ++mi)
#pragma unroll
    for (int r = 0; r < 4; ++r) {
      v1_[mi][r] = 3.4e38f; v2_[mi][r] = 3.4e38f; v3_[mi][r] = 3.4e38f;
      i1_[mi][r] = 0; i2_[mi][r] = 0;
    }

  // clean vmcnt slate: prologue x-loads / xsq-stores / esq-loads drained
  VWAIT(0);
  MEMFENCE();
  // prime: chunks 0..3 into slots 0..3 (16 loads/wave outstanding)
  STAGE(0, 0); STAGE(1, 1); STAGE(2, 2); STAGE(3, 3);

  f32x4 acc[2][4];
  for (int ctk = 0; ctk < 16; ++ctk) {
#pragma unroll
    for (int mi = 0; mi < 2; ++mi)
#pragma unroll
      for (int nj = 0; nj < 4; ++nj) acc[mi][nj] = (f32x4){0.f, 0.f, 0.f, 0.f};

#pragma unroll
    for (int ks2 = 0; ks2 < 4; ++ks2) {
      const int q = ctk * 4 + ks2;
      if (q < 60) {                       // uniform branch
        STAGE(q + 4, (q + 4) % 6);
        VWAIT(16);                        // chunk q landed (16 newer remain)
      } else if (q == 60) { VWAIT(12);
      } else if (q == 61) { VWAIT(8);
      } else if (q == 62) { VWAIT(4);
      } else              { VWAIT(0); }
      __builtin_amdgcn_s_barrier();       // raw: in-flight loads NOT drained
      MEMFENCE();

      const char* bb = esb + (q % 6) * 8192;
#pragma unroll
      for (int h = 0; h < 2; ++h) {
        f16x8 bfr[4];
#pragma unroll
        for (int njj = 0; njj < 4; ++njj)
          bfr[njj] = *reinterpret_cast<const f16x8*>(
              bb + (h * 4 + njj) * 1024 + lane * 16);
        const int sg = ks2 * 2 + h;
#pragma unroll
        for (int mi = 0; mi < 2; ++mi)
#pragma unroll
          for (int njj = 0; njj < 4; ++njj)
            acc[mi][njj] = __builtin_amdgcn_mfma_f32_16x16x32_f16(
                a[mi][sg], bfr[njj], acc[mi][njj], 0, 0, 0);
      }
    }

    // epilogue: distances for codes [ctk*64, +64); esq from LDS (lgkm only)
#pragma unroll
    for (int njj = 0; njj < 4; ++njj) {
      const int code = ctk * 64 + njj * 16 + col;
      const float sqv = es_sq[code];
#pragma unroll
      for (int mi = 0; mi < 2; ++mi)
#pragma unroll
        for (int r = 0; r < 4; ++r) {
          const float d = fmaf(-2.f, acc[mi][njj][r], sqv);
          if (d < v1_[mi][r]) {
            v3_[mi][r] = v2_[mi][r]; v2_[mi][r] = v1_[mi][r];
            i2_[mi][r] = i1_[mi][r];
            v1_[mi][r] = d; i1_[mi][r] = code;
          } else if (d < v2_[mi][r]) {
            v3_[mi][r] = v2_[mi][r]; v2_[mi][r] = d; i2_[mi][r] = code;
          } else if (d < v3_[mi][r]) {
            v3_[mi][r] = d;
          }
        }
    }
  }

  // cross-lane top-3 merge over the 16 code-columns (masks 1,2,4,8)
#pragma unroll
  for (int mi = 0; mi < 2; ++mi)
#pragma unroll
    for (int r = 0; r < 4; ++r) {
      float mv1 = v1_[mi][r], mv2 = v2_[mi][r], mv3 = v3_[mi][r];
      int mi1 = i1_[mi][r], mi2 = i2_[mi][r];
#pragma unroll
      for (int m = 1; m <= 8; m <<= 1) {
        const float ov1 = __shfl_xor(mv1, m, 64);
        const float ov2 = __shfl_xor(mv2, m, 64);
        const float ov3 = __shfl_xor(mv3, m, 64);
        const int oi1 = __shfl_xor(mi1, m, 64);
        const int oi2 = __shfl_xor(mi2, m, 64);
        const bool oW = (ov1 < mv1) || (ov1 == mv1 && oi1 < mi1);
        const float wv1 = oW ? ov1 : mv1, wv2 = oW ? ov2 : mv2, wv3 = oW ? ov3 : mv3;
        const int wi1 = oW ? oi1 : mi1, wi2 = oW ? oi2 : mi2;
        const float lv1 = oW ? mv1 : ov1, lv2 = oW ? mv2 : ov2;
        const int li1 = oW ? mi1 : oi1;
        const bool w2 = (wv2 < lv1) || (wv2 == lv1 && wi2 < li1);
        mv1 = wv1; mi1 = wi1;
        mv2 = w2 ? wv2 : lv1;
        mi2 = w2 ? wi2 : li1;
        mv3 = w2 ? fminf(wv3, lv1) : fminf(wv2, lv2);
      }
      if (col == 0) {
        const int t = tw + mi * 16 + kq * 4 + r;
        outIdxF[t] = (float)mi1;
        bestDist[t] = mv1;
        atomicAdd(&hist[mi1], 1);
        if (mv2 - mv1 < EPS) {
          const unsigned full = (mv3 - mv1 < EPS) ? 0x80000000u : 0u;
          const int pp = atomicAdd(fixCount, 1);
          fixList[pp * 2] = (unsigned)t | full;
          fixList[pp * 2 + 1] = (unsigned)mi2;
        }
      }
      i1_[mi][r] = mi1;  // merged, uniform across the kq group's 16 lanes
    }

  // fused gather: 32 tokens, index broadcast via shfl (wave-local)
#pragma unroll
  for (int i = 0; i < 32; ++i) {
    const int id = __shfl(i1_[i >> 4][i & 3], ((i >> 2) & 3) * 16, 64);
    const float4 q = reinterpret_cast<const float4*>(&e[id * DIM])[lane];
    reinterpret_cast<float4*>(&outQ[(tw + i) * DIM])[lane] = q;
  }
}

// ---- fixup: pairwise exact check (common) or full rescan (rare) ----
__global__ __launch_bounds__(256) void vq_fixup(
    const float* __restrict__ x, const float* __restrict__ e,
    const int* __restrict__ fixCount, const unsigned int* __restrict__ fixList,
    float* __restrict__ outIdxF, float* __restrict__ outQ,
    float* __restrict__ bestDist, int* __restrict__ hist) {
  const int n = *fixCount;
  const int tid = threadIdx.x;
  __shared__ float xrow[256];
  __shared__ float rv[4];
  __shared__ int ri[4];
  __shared__ int sOld, sFi;
  for (int it = blockIdx.x; it < n; it += gridDim.x) {
    const unsigned e0 = fixList[it * 2];
    const int t = (int)(e0 & 0x3FFFFFFFu);
    const bool full = (e0 >> 31) != 0u;
    if (!full) {
      if (tid < 64) {
        const int i1 = (int)outIdxF[t];
        const int i2 = (int)fixList[it * 2 + 1];
        const float4 xv = reinterpret_cast<const float4*>(&x[t * DIM])[tid];
        const float4 e1 = reinterpret_cast<const float4*>(&e[i1 * DIM])[tid];
        const float4 e2 = reinterpret_cast<const float4*>(&e[i2 * DIM])[tid];
        float d1 = (xv.x - e1.x) * (xv.x - e1.x) + (xv.y - e1.y) * (xv.y - e1.y) +
                   (xv.z - e1.z) * (xv.z - e1.z) + (xv.w - e1.w) * (xv.w - e1.w);
        float d2 = (xv.x - e2.x) * (xv.x - e2.x) + (xv.y - e2.y) * (xv.y - e2.y) +
                   (xv.z - e2.z) * (xv.z - e2.z) + (xv.w - e2.w) * (xv.w - e2.w);
#pragma unroll
        for (int m = 32; m > 0; m >>= 1) {
          d1 += __shfl_xor(d1, m, 64);
          d2 += __shfl_xor(d2, m, 64);
        }
        const bool swap2 = (d2 < d1) || (d2 == d1 && i2 < i1);
        const int wIdx = swap2 ? i2 : i1;
        const float wD = swap2 ? d2 : d1;
        if (tid == 0) {
          bestDist[t] = wD;
          if (wIdx != i1) {
            atomicSub(&hist[i1], 1);
            atomicAdd(&hist[wIdx], 1);
            outIdxF[t] = (float)wIdx;
          }
        }
        if (swap2) {
          const float4 q = reinterpret_cast<const float4*>(&e[wIdx * DIM])[tid];
          reinterpret_cast<float4*>(&outQ[t * DIM])[tid] = q;
        }
      }
    } else {
      __syncthreads();
      if (tid < 64) ((float4*)xrow)[tid] = ((const float4*)&x[t * DIM])[tid];
      __syncthreads();
      float bv = 3.4e38f; int bi = 0;
      for (int c = tid; c < KC; c += 256) {
        float s = 0.f;
#pragma unroll
        for (int d = 0; d < DIM; d += 4) {
          const float4 ev = *(const float4*)&e[c * DIM + d];
          const float d0 = xrow[d] - ev.x, d1 = xrow[d + 1] - ev.y;
          const float d2 = xrow[d + 2] - ev.z, d3 = xrow[d + 3] - ev.w;
          s += d0 * d0 + d1 * d1 + d2 * d2 + d3 * d3;
        }
        if (s < bv) { bv = s; bi = c; }
      }
#pragma unroll
      for (int m = 1; m <= 32; m <<= 1) {
        const float ob = __shfl_xor(bv, m, 64);
        const int oi = __shfl_xor(bi, m, 64);
        if (ob < bv || (ob == bv && oi < bi)) { bv = ob; bi = oi; }
      }
      const int lane = tid & 63, wv = tid >> 6;
      if (lane == 0) { rv[wv] = bv; ri[wv] = bi; }
      __syncthreads();
      if (tid == 0) {
        float fb = rv[0]; int fi = ri[0];
        for (int k = 1; k < 4; ++k)
          if (rv[k] < fb || (rv[k] == fb && ri[k] < fi)) { fb = rv[k]; fi = ri[k]; }
        sOld = (int)outIdxF[t];
        sFi = fi;
        bestDist[t] = fb;
        if (fi != sOld) {
          atomicSub(&hist[sOld], 1);
          atomicAdd(&hist[fi], 1);
          outIdxF[t] = (float)fi;
        }
      }
      __syncthreads();
      if (sFi != sOld) outQ[t * DIM + tid] = e[sFi * DIM + tid];
      __syncthreads();
    }
  }
}

// ---- final scalars: loss from xsq+bestDist; perplexity from hist ----
__global__ __launch_bounds__(1024) void vq_final(
    const int* __restrict__ hist, const float* __restrict__ xsq,
    const float* __restrict__ bestDist, float* __restrict__ outLoss,
    float* __restrict__ outPerp) {
  const int tid = threadIdx.x;
  float ls = 0.f;
  for (int i = 0; i < 64; ++i) {
    const int t = tid + i * 1024;
    ls += xsq[t] + bestDist[t];
  }
  const float p = (float)hist[tid] * (1.f / 65536.f);
  float ent = p * logf(p + 1e-10f);
#pragma unroll
  for (int o = 32; o > 0; o >>= 1) {
    ls += __shfl_down(ls, o, 64);
    ent += __shfl_down(ent, o, 64);
  }
  __shared__ float lbuf[16], ebuf[16];
  const int lane = tid & 63, wv = tid >> 6;
  if (lane == 0) { lbuf[wv] = ls; ebuf[wv] = ent; }
  __syncthreads();
  if (tid == 0) {
    float L = 0.f, E = 0.f;
    for (int i = 0; i < 16; ++i) { L += lbuf[i]; E += ebuf[i]; }
    *outLoss = 0.25f * (L / 16777216.f);
    *outPerp = expf(-E);
  }
}

extern "C" void kernel_launch(void* const* d_in, const int* in_sizes, int n_in,
                              void* d_out, int out_size, void* d_ws, size_t ws_size,
                              hipStream_t stream) {
  const float* x = (const float*)d_in[0];  // [65536, 256]
  const float* e = (const float*)d_in[1];  // [1024, 256]
  float* out = (float*)d_out;
  float* outQ = out;                 // 16777216 floats
  float* outLoss = out + 16777216;
  float* outPerp = out + 16777217;
  float* outIdxF = out + 16777218;   // 65536 floats

  char* ws = (char*)d_ws;
  int*   hist     = (int*)ws;                     // 4 KB
  float* esq      = (float*)(ws + 4096);          // 4 KB
  float* xsq      = (float*)(ws + 8192);          // 256 KB
  float* bestDist = (float*)(ws + 270336);        // 256 KB
  int*   fixCount = (int*)(ws + 532480);          // 16 B
  unsigned int* fixList = (unsigned int*)(ws + 532496);  // 512 KB (2/entry)
  unsigned short* e_f16 = (unsigned short*)(ws + 1056784);  // 512 KB
  // total ws use ~1.57 MB

  vq_prep_e<<<128, 256, 0, stream>>>(e, e_f16, esq, hist, fixCount);
  vq_argmin<<<NTOK / 64, 128, 0, stream>>>(x, e_f16, esq, e, outIdxF, outQ,
                                           bestDist, xsq, hist, fixCount, fixList);
  vq_fixup<<<256, 256, 0, stream>>>(x, e, fixCount, fixList, outIdxF, outQ,
                                    bestDist, hist);
  vq_final<<<1, 1024, 0, stream>>>(hist, xsq, bestDist, outLoss, outPerp);
}

// Round 18
// 200.469 us; speedup vs baseline: 1.3019x; 1.1195x over previous
//
#include <hip/hip_runtime.h>

#define NTOK 65536
#define DIM 256
#define KC 1024
#define EPS 0.08f

typedef __attribute__((ext_vector_type(8))) _Float16 f16x8;
typedef __attribute__((ext_vector_type(8))) unsigned short u16x8;
typedef __attribute__((ext_vector_type(4))) float f32x4;

static __device__ __forceinline__ unsigned short f16bits(float f) {
  _Float16 h = (_Float16)f;
  return __builtin_bit_cast(unsigned short, h);
}

// ---- e: fp32 -> fp16 FRAGMENT-MAJOR global image + esq; zero scalars ----
// Chunk c = ctk*32 + s*4 + njj (1 KB each), ctk in [0,16): lane = kq*16+col
// holds e[ctk*64 + njj*16 + col][s*32 + kq*8 + j].
__global__ __launch_bounds__(256) void vq_prep_e(const float* __restrict__ e,
                                                 unsigned short* __restrict__ eg,
                                                 float* __restrict__ esq,
                                                 int* __restrict__ hist,
                                                 int* __restrict__ fixCount) {
  const int gid = blockIdx.x * 256 + threadIdx.x;
  const int t = gid >> 5;
  const int o = gid & 31;
  const float4 v0 = *reinterpret_cast<const float4*>(&e[t * DIM + o * 8]);
  const float4 v1 = *reinterpret_cast<const float4*>(&e[t * DIM + o * 8 + 4]);
  u16x8 u;
  u[0] = f16bits(v0.x); u[1] = f16bits(v0.y); u[2] = f16bits(v0.z); u[3] = f16bits(v0.w);
  u[4] = f16bits(v1.x); u[5] = f16bits(v1.y); u[6] = f16bits(v1.z); u[7] = f16bits(v1.w);
  const int ctk = t >> 6, njj = (t >> 4) & 3, col = t & 15;
  const int s = o >> 2, kq = o & 3;
  char* dst = (char*)eg + ((ctk * 32 + s * 4 + njj) << 10) + ((kq * 16 + col) << 4);
  *reinterpret_cast<u16x8*>(dst) = u;
  float p = v0.x * v0.x + v0.y * v0.y + v0.z * v0.z + v0.w * v0.w +
            v1.x * v1.x + v1.y * v1.y + v1.z * v1.z + v1.w * v1.w;
#pragma unroll
  for (int m = 16; m > 0; m >>= 1) p += __shfl_xor(p, m, 64);
  if (o == 0) esq[t] = p;
  if (blockIdx.x < 4) hist[blockIdx.x * 256 + threadIdx.x] = 0;
  if (gid == 0) *fixCount = 0;
}

// ---- x: fp32 -> fp16 FRAGMENT-MAJOR image (B-operand layout) + xsq ----
__global__ __launch_bounds__(256) void vq_prep_x(const float* __restrict__ x,
                                                 unsigned short* __restrict__ xg,
                                                 float* __restrict__ xsq) {
  const int gid = blockIdx.x * 256 + threadIdx.x;  // 2097152 items
  const int t = gid >> 5;   // token
  const int o = gid & 31;   // k-octet
  const float4 v0 = *reinterpret_cast<const float4*>(&x[t * DIM + o * 8]);
  const float4 v1 = *reinterpret_cast<const float4*>(&x[t * DIM + o * 8 + 4]);
  u16x8 u;
  u[0] = f16bits(v0.x); u[1] = f16bits(v0.y); u[2] = f16bits(v0.z); u[3] = f16bits(v0.w);
  u[4] = f16bits(v1.x); u[5] = f16bits(v1.y); u[6] = f16bits(v1.z); u[7] = f16bits(v1.w);
  const int s = o >> 2, kq = o & 3;
  char* dst = (char*)xg + (((t >> 4) * 8 + s) << 10) + ((kq * 16 + (t & 15)) << 4);
  *reinterpret_cast<u16x8*>(dst) = u;
  float p = v0.x * v0.x + v0.y * v0.y + v0.z * v0.z + v0.w * v0.w +
            v1.x * v1.x + v1.y * v1.y + v1.z * v1.z + v1.w * v1.w;
#pragma unroll
  for (int m = 16; m > 0; m >>= 1) p += __shfl_xor(p, m, 64);
  if (o == 0) xsq[t] = p;
}

// ---- FLIPPED argmin: e resident in registers, x streamed ----
// Block = 4 waves; wave w owns 32 codes (partition pw = cp*4+w). Records
// are PER-WAVE (fixes r17's 4-waves-clobber-one-slot bug).
__global__ __launch_bounds__(256, 3) void vq_argmin(
    const unsigned short* __restrict__ xg, const unsigned short* __restrict__ eg,
    const float* __restrict__ esq, float* __restrict__ rV1,
    unsigned int* __restrict__ rI1, float* __restrict__ rV2,
    unsigned int* __restrict__ rI2) {
  const int lane = threadIdx.x & 63, w = threadIdx.x >> 6;
  const int col = lane & 15, kq = lane >> 4;
  const int cp = blockIdx.x & 7, tb = blockIdx.x >> 3;
  const int cbase = cp * 128 + w * 32;
  const int ctk = cbase >> 6;        // 64-code group
  const int njb = (w & 1) * 2;       // njj base within group
  const int pw = cp * 4 + w;         // wave-partition id, codes ascend with pw

  // e-fragments resident: 16 frags = 64 VGPR; esq for this lane's 8 codes
  f16x8 ae[8][2];
#pragma unroll
  for (int s = 0; s < 8; ++s)
#pragma unroll
    for (int cg = 0; cg < 2; ++cg)
      ae[s][cg] = *reinterpret_cast<const f16x8*>(
          (const char*)eg + ((ctk * 32 + s * 4 + njb + cg) << 10) + (lane << 4));
  float esr[2][4];
#pragma unroll
  for (int cg = 0; cg < 2; ++cg)
#pragma unroll
    for (int r = 0; r < 4; ++r)
      esr[cg][r] = esq[cbase + cg * 16 + kq * 4 + r];

  for (int i = 0; i < 16; ++i) {
    const int tsub = tb * 16 + i;
    f32x4 acc[2];
    acc[0] = (f32x4){0.f, 0.f, 0.f, 0.f};
    acc[1] = (f32x4){0.f, 0.f, 0.f, 0.f};
#pragma unroll
    for (int s = 0; s < 8; ++s) {
      const f16x8 bx = *reinterpret_cast<const f16x8*>(
          (const char*)xg + ((tsub * 8 + s) << 10) + (lane << 4));
      acc[0] = __builtin_amdgcn_mfma_f32_16x16x32_f16(ae[s][0], bx, acc[0], 0, 0, 0);
      acc[1] = __builtin_amdgcn_mfma_f32_16x16x32_f16(ae[s][1], bx, acc[1], 0, 0, 0);
    }
    // per lane: token = tsub*16 + col; 8 codes (cg,r) ascending -> top-3
    float v1 = 3.4e38f, v2 = 3.4e38f, v3 = 3.4e38f;
    int i1 = 0, i2 = 0;
#pragma unroll
    for (int cg = 0; cg < 2; ++cg)
#pragma unroll
      for (int r = 0; r < 4; ++r) {
        const int code = cbase + cg * 16 + kq * 4 + r;
        const float d = fmaf(-2.f, acc[cg][r], esr[cg][r]);
        if (d < v1) { v3 = v2; v2 = v1; i2 = i1; v1 = d; i1 = code; }
        else if (d < v2) { v3 = v2; v2 = d; i2 = code; }
        else if (d < v3) { v3 = d; }
      }
    // cross-kq merge (masks 16, 32): exact top-3 over this wave's 32 codes
#pragma unroll
    for (int m = 16; m <= 32; m <<= 1) {
      const float ov1 = __shfl_xor(v1, m, 64);
      const float ov2 = __shfl_xor(v2, m, 64);
      const float ov3 = __shfl_xor(v3, m, 64);
      const int oi1 = __shfl_xor(i1, m, 64);
      const int oi2 = __shfl_xor(i2, m, 64);
      const bool oW = (ov1 < v1) || (ov1 == v1 && oi1 < i1);
      const float wv1 = oW ? ov1 : v1, wv2 = oW ? ov2 : v2, wv3 = oW ? ov3 : v3;
      const int wi1 = oW ? oi1 : i1, wi2 = oW ? oi2 : i2;
      const float lv1 = oW ? v1 : ov1, lv2 = oW ? v2 : ov2;
      const int li1 = oW ? i1 : oi1;
      const bool w2 = (wv2 < lv1) || (wv2 == lv1 && wi2 < li1);
      v1 = wv1; i1 = wi1;
      v2 = w2 ? wv2 : lv1;
      i2 = w2 ? wi2 : li1;
      v3 = w2 ? fminf(wv3, lv1) : fminf(wv2, lv2);
    }
    if (kq == 0) {  // lanes 0..15: one record per (wave-partition, token)
      const int rb = pw * NTOK + tsub * 16 + col;
      rV1[rb] = v1;
      rI1[rb] = (unsigned)i1 | ((v3 - v1 < EPS) ? 0x80000000u : 0u);
      rV2[rb] = v2;
      rI2[rb] = (unsigned)i2;
    }
  }
}

// ---- merge 32 wave-partition top-2(+flag) -> idx, bestDist, hist, fix ----
__global__ __launch_bounds__(256) void vq_finish1(
    const float* __restrict__ rV1, const unsigned int* __restrict__ rI1,
    const float* __restrict__ rV2, const unsigned int* __restrict__ rI2,
    const float* __restrict__ xsq, float* __restrict__ outIdxF,
    float* __restrict__ bestDist, int* __restrict__ hist,
    int* __restrict__ fixCount, unsigned int* __restrict__ fixList) {
  const int t = blockIdx.x * 256 + threadIdx.x;
  float m1 = 3.4e38f, m2 = 3.4e38f, m3 = 3.4e38f;
  int mi1 = 0x7FFFFFFF, mi2 = 0x7FFFFFFF;
  float minFlagV1 = 3.4e38f;
#pragma unroll
  for (int p = 0; p < 32; ++p) {
    const int rb = p * NTOK + t;
    const float a1 = rV1[rb];
    const unsigned u1 = rI1[rb];
    const float a2 = rV2[rb];
    const int ai2 = (int)rI2[rb];
    const int ai1 = (int)(u1 & 0x7FFFFFFFu);
    if (u1 >> 31) minFlagV1 = fminf(minFlagV1, a1);
    if (a1 < m1 || (a1 == m1 && ai1 < mi1)) {
      m3 = m2; m2 = m1; mi2 = mi1; m1 = a1; mi1 = ai1;
    } else if (a1 < m2 || (a1 == m2 && ai1 < mi2)) {
      m3 = m2; m2 = a1; mi2 = ai1;
    } else if (a1 < m3) m3 = a1;
    if (a2 < m1 || (a2 == m1 && ai2 < mi1)) {
      m3 = m2; m2 = m1; mi2 = mi1; m1 = a2; mi1 = ai2;
    } else if (a2 < m2 || (a2 == m2 && ai2 < mi2)) {
      m3 = m2; m2 = a2; mi2 = ai2;
    } else if (a2 < m3) m3 = a2;
  }
  outIdxF[t] = (float)mi1;
  bestDist[t] = xsq[t] + m1;  // FULL squared distance
  atomicAdd(&hist[mi1], 1);
  if (m2 - m1 < EPS) {
    const bool full = (m3 - m1 < EPS) || (minFlagV1 - m1 < EPS);
    const int p = atomicAdd(fixCount, 1);
    fixList[p * 2] = (unsigned)t | (full ? 0x80000000u : 0u);
    fixList[p * 2 + 1] = (unsigned)(mi2 & 0x3FF);
  }
}

// ---- gather: outIdxF -> outQ (after records consumed) ----
__global__ __launch_bounds__(256) void vq_gather(
    const float* __restrict__ e, const float* __restrict__ outIdxF,
    float* __restrict__ outQ) {
  const int lane = threadIdx.x & 63, w = threadIdx.x >> 6;
  const int t0 = blockIdx.x * 64 + w * 16;
#pragma unroll
  for (int i = 0; i < 16; ++i) {
    const int t = t0 + i;
    const int id = (int)outIdxF[t];
    const float4 q = reinterpret_cast<const float4*>(&e[id * DIM])[lane];
    reinterpret_cast<float4*>(&outQ[t * DIM])[lane] = q;
  }
}

// ---- fixup: pairwise exact check (common) or full rescan (rare) ----
__global__ __launch_bounds__(256) void vq_fixup(
    const float* __restrict__ x, const float* __restrict__ e,
    const int* __restrict__ fixCount, const unsigned int* __restrict__ fixList,
    float* __restrict__ outIdxF, float* __restrict__ outQ,
    float* __restrict__ bestDist, int* __restrict__ hist) {
  const int n = *fixCount;
  const int tid = threadIdx.x;
  __shared__ float xrow[256];
  __shared__ float rv[4];
  __shared__ int ri[4];
  __shared__ int sOld, sFi;
  for (int it = blockIdx.x; it < n; it += gridDim.x) {
    const unsigned e0 = fixList[it * 2];
    const int t = (int)(e0 & 0x3FFFFFFFu);
    const bool full = (e0 >> 31) != 0u;
    if (!full) {
      if (tid < 64) {
        const int i1 = (int)outIdxF[t];
        const int i2 = (int)fixList[it * 2 + 1];
        const float4 xv = reinterpret_cast<const float4*>(&x[t * DIM])[tid];
        const float4 e1 = reinterpret_cast<const float4*>(&e[i1 * DIM])[tid];
        const float4 e2 = reinterpret_cast<const float4*>(&e[i2 * DIM])[tid];
        float d1 = (xv.x - e1.x) * (xv.x - e1.x) + (xv.y - e1.y) * (xv.y - e1.y) +
                   (xv.z - e1.z) * (xv.z - e1.z) + (xv.w - e1.w) * (xv.w - e1.w);
        float d2 = (xv.x - e2.x) * (xv.x - e2.x) + (xv.y - e2.y) * (xv.y - e2.y) +
                   (xv.z - e2.z) * (xv.z - e2.z) + (xv.w - e2.w) * (xv.w - e2.w);
#pragma unroll
        for (int m = 32; m > 0; m >>= 1) {
          d1 += __shfl_xor(d1, m, 64);
          d2 += __shfl_xor(d2, m, 64);
        }
        const bool swap2 = (d2 < d1) || (d2 == d1 && i2 < i1);
        const int wIdx = swap2 ? i2 : i1;
        const float wD = swap2 ? d2 : d1;
        if (tid == 0) {
          bestDist[t] = wD;
          if (wIdx != i1) {
            atomicSub(&hist[i1], 1);
            atomicAdd(&hist[wIdx], 1);
            outIdxF[t] = (float)wIdx;
          }
        }
        if (swap2) {
          const float4 q = reinterpret_cast<const float4*>(&e[wIdx * DIM])[tid];
          reinterpret_cast<float4*>(&outQ[t * DIM])[tid] = q;
        }
      }
    } else {
      __syncthreads();
      if (tid < 64) ((float4*)xrow)[tid] = ((const float4*)&x[t * DIM])[tid];
      __syncthreads();
      float bv = 3.4e38f; int bi = 0;
      for (int c = tid; c < KC; c += 256) {
        float s = 0.f;
#pragma unroll
        for (int d = 0; d < DIM; d += 4) {
          const float4 ev = *(const float4*)&e[c * DIM + d];
          const float d0 = xrow[d] - ev.x, d1 = xrow[d + 1] - ev.y;
          const float d2 = xrow[d + 2] - ev.z, d3 = xrow[d + 3] - ev.w;
          s += d0 * d0 + d1 * d1 + d2 * d2 + d3 * d3;
        }
        if (s < bv) { bv = s; bi = c; }
      }
#pragma unroll
      for (int m = 1; m <= 32; m <<= 1) {
        const float ob = __shfl_xor(bv, m, 64);
        const int oi = __shfl_xor(bi, m, 64);
        if (ob < bv || (ob == bv && oi < bi)) { bv = ob; bi = oi; }
      }
      const int lane = tid & 63, wv = tid >> 6;
      if (lane == 0) { rv[wv] = bv; ri[wv] = bi; }
      __syncthreads();
      if (tid == 0) {
        float fb = rv[0]; int fi = ri[0];
        for (int k = 1; k < 4; ++k)
          if (rv[k] < fb || (rv[k] == fb && ri[k] < fi)) { fb = rv[k]; fi = ri[k]; }
        sOld = (int)outIdxF[t];
        sFi = fi;
        bestDist[t] = fb;
        if (fi != sOld) {
          atomicSub(&hist[sOld], 1);
          atomicAdd(&hist[fi], 1);
          outIdxF[t] = (float)fi;
        }
      }
      __syncthreads();
      if (sFi != sOld) outQ[t * DIM + tid] = e[sFi * DIM + tid];
      __syncthreads();
    }
  }
}

// ---- final scalars: loss = 0.25 * mean(bestDist); perplexity ----
__global__ __launch_bounds__(1024) void vq_final(
    const int* __restrict__ hist, const float* __restrict__ bestDist,
    float* __restrict__ outLoss, float* __restrict__ outPerp) {
  const int tid = threadIdx.x;
  float ls = 0.f;
  for (int i = 0; i < 64; ++i) ls += bestDist[tid + i * 1024];
  const float p = (float)hist[tid] * (1.f / 65536.f);
  float ent = p * logf(p + 1e-10f);
#pragma unroll
  for (int o = 32; o > 0; o >>= 1) {
    ls += __shfl_down(ls, o, 64);
    ent += __shfl_down(ent, o, 64);
  }
  __shared__ float lbuf[16], ebuf[16];
  const int lane = tid & 63, wv = tid >> 6;
  if (lane == 0) { lbuf[wv] = ls; ebuf[wv] = ent; }
  __syncthreads();
  if (tid == 0) {
    float L = 0.f, E = 0.f;
    for (int i = 0; i < 16; ++i) { L += lbuf[i]; E += ebuf[i]; }
    *outLoss = 0.25f * (L / 16777216.f);
    *outPerp = expf(-E);
  }
}

extern "C" void kernel_launch(void* const* d_in, const int* in_sizes, int n_in,
                              void* d_out, int out_size, void* d_ws, size_t ws_size,
                              hipStream_t stream) {
  const float* x = (const float*)d_in[0];  // [65536, 256]
  const float* e = (const float*)d_in[1];  // [1024, 256]
  float* out = (float*)d_out;
  float* outQ = out;                 // 16777216 floats
  float* outLoss = out + 16777216;
  float* outPerp = out + 16777217;
  float* outIdxF = out + 16777218;   // 65536 floats

  // scratch inside d_out's quantized region (rewritten every call, fully
  // consumed by vq_finish1 before vq_gather/vq_fixup write outQ):
  unsigned short* xg = (unsigned short*)d_out;        // bytes [0, 33554432)
  float* rV1 = out + 8388608;                         // [33554432, 41943040)
  unsigned int* rI1 = (unsigned int*)(out + 10485760);// [41943040, 50331648)
  float* rV2 = out + 12582912;                        // [50331648, 58720256)
  unsigned int* rI2 = (unsigned int*)(out + 14680064);// [58720256, 67108864)
  // records end exactly at outLoss (byte 67108864): no overlap.

  char* ws = (char*)d_ws;
  int*   hist     = (int*)ws;                     // 4 KB
  float* esq      = (float*)(ws + 4096);          // 4 KB
  float* xsq      = (float*)(ws + 8192);          // 256 KB
  float* bestDist = (float*)(ws + 270336);        // 256 KB
  int*   fixCount = (int*)(ws + 532480);          // 16 B
  unsigned int* fixList = (unsigned int*)(ws + 532496);  // 512 KB
  unsigned short* e_f16 = (unsigned short*)(ws + 1056784);  // 512 KB

  vq_prep_e<<<128, 256, 0, stream>>>(e, e_f16, esq, hist, fixCount);
  vq_prep_x<<<8192, 256, 0, stream>>>(x, xg, xsq);
  vq_argmin<<<2048, 256, 0, stream>>>(xg, e_f16, esq, rV1, rI1, rV2, rI2);
  vq_finish1<<<256, 256, 0, stream>>>(rV1, rI1, rV2, rI2, xsq, outIdxF,
                                      bestDist, hist, fixCount, fixList);
  vq_gather<<<1024, 256, 0, stream>>>(e, outIdxF, outQ);
  vq_fixup<<<256, 256, 0, stream>>>(x, e, fixCount, fixList, outIdxF, outQ,
                                    bestDist, hist);
  vq_final<<<1, 1024, 0, stream>>>(hist, bestDist, outLoss, outPerp);
}

// Round 19
// 178.416 us; speedup vs baseline: 1.4628x; 1.1236x over previous
//
#include <hip/hip_runtime.h>

#define NTOK 65536
#define DIM 256
#define KC 1024
#define EPS 0.08f

typedef __attribute__((ext_vector_type(8))) _Float16 f16x8;
typedef __attribute__((ext_vector_type(8))) unsigned short u16x8;
typedef __attribute__((ext_vector_type(4))) float f32x4;

static __device__ __forceinline__ unsigned short f16bits(float f) {
  _Float16 h = (_Float16)f;
  return __builtin_bit_cast(unsigned short, h);
}
// monotone pack: key orders like (dist, code); low 10 bits = code
static __device__ __forceinline__ unsigned packKey(float d, int code) {
  unsigned b = __float_as_uint(d);
  b = ((int)b < 0) ? ~b : (b | 0x80000000u);
  return (b & ~1023u) | (unsigned)code;
}
static __device__ __forceinline__ float decKey(unsigned k) {
  unsigned b = k & ~1023u;
  b = (b & 0x80000000u) ? (b ^ 0x80000000u) : ~b;
  return __uint_as_float(b);
}

// ---- e: fp32 -> fp16 FRAGMENT-MAJOR global image + esq; zero scalars ----
__global__ __launch_bounds__(256) void vq_prep_e(const float* __restrict__ e,
                                                 unsigned short* __restrict__ eg,
                                                 float* __restrict__ esq,
                                                 int* __restrict__ hist,
                                                 int* __restrict__ fixCount) {
  const int gid = blockIdx.x * 256 + threadIdx.x;
  const int t = gid >> 5;
  const int o = gid & 31;
  const float4 v0 = *reinterpret_cast<const float4*>(&e[t * DIM + o * 8]);
  const float4 v1 = *reinterpret_cast<const float4*>(&e[t * DIM + o * 8 + 4]);
  u16x8 u;
  u[0] = f16bits(v0.x); u[1] = f16bits(v0.y); u[2] = f16bits(v0.z); u[3] = f16bits(v0.w);
  u[4] = f16bits(v1.x); u[5] = f16bits(v1.y); u[6] = f16bits(v1.z); u[7] = f16bits(v1.w);
  const int ctk = t >> 6, njj = (t >> 4) & 3, col = t & 15;
  const int s = o >> 2, kq = o & 3;
  char* dst = (char*)eg + ((ctk * 32 + s * 4 + njj) << 10) + ((kq * 16 + col) << 4);
  *reinterpret_cast<u16x8*>(dst) = u;
  float p = v0.x * v0.x + v0.y * v0.y + v0.z * v0.z + v0.w * v0.w +
            v1.x * v1.x + v1.y * v1.y + v1.z * v1.z + v1.w * v1.w;
#pragma unroll
  for (int m = 16; m > 0; m >>= 1) p += __shfl_xor(p, m, 64);
  if (o == 0) esq[t] = p;
  if (blockIdx.x < 4) hist[blockIdx.x * 256 + threadIdx.x] = 0;
  if (gid == 0) *fixCount = 0;
}

// ---- x: fp32 -> fp16 FRAGMENT-MAJOR image (B-operand layout) + xsq ----
__global__ __launch_bounds__(256) void vq_prep_x(const float* __restrict__ x,
                                                 unsigned short* __restrict__ xg,
                                                 float* __restrict__ xsq) {
  const int gid = blockIdx.x * 256 + threadIdx.x;
  const int t = gid >> 5;
  const int o = gid & 31;
  const float4 v0 = *reinterpret_cast<const float4*>(&x[t * DIM + o * 8]);
  const float4 v1 = *reinterpret_cast<const float4*>(&x[t * DIM + o * 8 + 4]);
  u16x8 u;
  u[0] = f16bits(v0.x); u[1] = f16bits(v0.y); u[2] = f16bits(v0.z); u[3] = f16bits(v0.w);
  u[4] = f16bits(v1.x); u[5] = f16bits(v1.y); u[6] = f16bits(v1.z); u[7] = f16bits(v1.w);
  const int s = o >> 2, kq = o & 3;
  char* dst = (char*)xg + (((t >> 4) * 8 + s) << 10) + ((kq * 16 + (t & 15)) << 4);
  *reinterpret_cast<u16x8*>(dst) = u;
  float p = v0.x * v0.x + v0.y * v0.y + v0.z * v0.z + v0.w * v0.w +
            v1.x * v1.x + v1.y * v1.y + v1.z * v1.z + v1.w * v1.w;
#pragma unroll
  for (int m = 16; m > 0; m >>= 1) p += __shfl_xor(p, m, 64);
  if (o == 0) xsq[t] = p;
}

// ---- FLIPPED argmin: e FORCED resident (asm loads), x streamed ----
// XCD-pinned: xcd g handles tokens [g*8192, (g+1)*8192) (4 MB = L2 size).
__global__ __launch_bounds__(256, 4) void vq_argmin(
    const unsigned short* __restrict__ xg, const unsigned short* __restrict__ eg,
    const float* __restrict__ esq, unsigned int* __restrict__ rK1,
    unsigned int* __restrict__ rK2, unsigned int* __restrict__ rK3) {
  const int lane = threadIdx.x & 63, w = threadIdx.x >> 6;
  const int col = lane & 15, kq = lane >> 4;
  const int g = blockIdx.x & 7;        // XCD (dispatch round-robin)
  const int j = blockIdx.x >> 3;
  const int cp = j & 7;                // code partition
  const int tb = g * 32 + (j >> 3);    // token-block, XCD-local
  const int cbase = cp * 128 + w * 32;
  const int ctk = cbase >> 6;
  const int njb = (w & 1) * 2;
  const int pw = cp * 4 + w;           // wave-partition id

  // e-fragments: 16 asm loads -> guaranteed register residency (64 VGPR)
  f16x8 ae[8][2];
#pragma unroll
  for (int s = 0; s < 8; ++s)
#pragma unroll
    for (int cg = 0; cg < 2; ++cg) {
      const char* ap =
          (const char*)eg + ((ctk * 32 + s * 4 + njb + cg) << 10) + (lane << 4);
      asm volatile("global_load_dwordx4 %0, %1, off"
                   : "=v"(ae[s][cg]) : "v"(ap) : "memory");
    }
  float esr[2][4];
#pragma unroll
  for (int cg = 0; cg < 2; ++cg)
#pragma unroll
    for (int r = 0; r < 4; ++r)
      esr[cg][r] = esq[cbase + cg * 16 + kq * 4 + r];
  asm volatile("s_waitcnt vmcnt(0)" ::: "memory");
  __builtin_amdgcn_sched_barrier(0);

  for (int i = 0; i < 16; ++i) {
    const int tsub = tb * 16 + i;
    f32x4 acc[2];
    acc[0] = (f32x4){0.f, 0.f, 0.f, 0.f};
    acc[1] = (f32x4){0.f, 0.f, 0.f, 0.f};
#pragma unroll
    for (int s = 0; s < 8; ++s) {
      const f16x8 bx = *reinterpret_cast<const f16x8*>(
          (const char*)xg + ((tsub * 8 + s) << 10) + (lane << 4));
      acc[0] = __builtin_amdgcn_mfma_f32_16x16x32_f16(ae[s][0], bx, acc[0], 0, 0, 0);
      acc[1] = __builtin_amdgcn_mfma_f32_16x16x32_f16(ae[s][1], bx, acc[1], 0, 0, 0);
    }
    // per lane: token = tsub*16 + col; 8 codes -> packed top-3
    unsigned k1 = 0xFFFFFFFFu, k2 = 0xFFFFFFFFu, k3 = 0xFFFFFFFFu;
#pragma unroll
    for (int cg = 0; cg < 2; ++cg)
#pragma unroll
      for (int r = 0; r < 4; ++r) {
        const int code = cbase + cg * 16 + kq * 4 + r;
        const unsigned k = packKey(fmaf(-2.f, acc[cg][r], esr[cg][r]), code);
        if (k < k1) { k3 = k2; k2 = k1; k1 = k; }
        else if (k < k2) { k3 = k2; k2 = k; }
        else if (k < k3) { k3 = k; }
      }
    // cross-kq merge (masks 16, 32): sorted-triple merge network
#pragma unroll
    for (int m = 16; m <= 32; m <<= 1) {
      const unsigned o1 = __shfl_xor((int)k1, m, 64);
      const unsigned o2 = __shfl_xor((int)k2, m, 64);
      const unsigned o3 = __shfl_xor((int)k3, m, 64);
      const unsigned t1 = max(k1, o1), lo2 = min(k2, o2);
      const unsigned nm1 = min(k1, o1);
      const unsigned nm2 = min(t1, lo2);
      const unsigned nm3 = min(min(max(t1, lo2), max(k2, o2)), min(k3, o3));
      k1 = nm1; k2 = nm2; k3 = nm3;
    }
    if (kq == 0) {  // lanes 0..15: one 12-B record per (wave-partition, token)
      const int rb = pw * NTOK + tsub * 16 + col;
      rK1[rb] = k1; rK2[rb] = k2; rK3[rb] = k3;
    }
  }
}

// ---- merge 32 wave-partition packed triples -> idx/bestDist/hist/fix ----
__global__ __launch_bounds__(256) void vq_finish1(
    const unsigned int* __restrict__ rK1, const unsigned int* __restrict__ rK2,
    const unsigned int* __restrict__ rK3, const float* __restrict__ xsq,
    float* __restrict__ outIdxF, float* __restrict__ bestDist,
    int* __restrict__ hist, int* __restrict__ fixCount,
    unsigned int* __restrict__ fixList) {
  const int t = blockIdx.x * 256 + threadIdx.x;
  unsigned m1 = 0xFFFFFFFFu, m2 = 0xFFFFFFFFu, m3 = 0xFFFFFFFFu;
  unsigned minFlagK1 = 0xFFFFFFFFu;
#pragma unroll
  for (int p = 0; p < 32; ++p) {
    const int rb = p * NTOK + t;
    const unsigned a1 = rK1[rb], a2 = rK2[rb], a3 = rK3[rb];
    if (decKey(a3) - decKey(a1) < EPS) minFlagK1 = min(minFlagK1, a1);
    const unsigned t1 = max(m1, a1), lo2 = min(m2, a2);
    const unsigned nm1 = min(m1, a1);
    const unsigned nm2 = min(t1, lo2);
    const unsigned nm3 = min(min(max(t1, lo2), max(m2, a2)), min(m3, a3));
    m1 = nm1; m2 = nm2; m3 = nm3;
  }
  const int mi1 = (int)(m1 & 1023u);
  const float d1 = decKey(m1);
  outIdxF[t] = (float)mi1;
  bestDist[t] = xsq[t] + d1;  // full squared distance (approx; exact on fixup)
  atomicAdd(&hist[mi1], 1);
  if (decKey(m2) - d1 < EPS) {
    const bool full = (decKey(m3) - d1 < EPS) || (decKey(minFlagK1) - d1 < EPS);
    const int p = atomicAdd(fixCount, 1);
    fixList[p * 2] = (unsigned)t | (full ? 0x80000000u : 0u);
    fixList[p * 2 + 1] = m2 & 1023u;
  }
}

// ---- gather: outIdxF -> outQ (records already consumed) ----
__global__ __launch_bounds__(256) void vq_gather(
    const float* __restrict__ e, const float* __restrict__ outIdxF,
    float* __restrict__ outQ) {
  const int lane = threadIdx.x & 63, w = threadIdx.x >> 6;
  const int t0 = blockIdx.x * 64 + w * 16;
#pragma unroll
  for (int i = 0; i < 16; ++i) {
    const int t = t0 + i;
    const int id = (int)outIdxF[t];
    const float4 q = reinterpret_cast<const float4*>(&e[id * DIM])[lane];
    reinterpret_cast<float4*>(&outQ[t * DIM])[lane] = q;
  }
}

// ---- fixup: pairwise exact check (common) or full rescan (rare) ----
__global__ __launch_bounds__(256) void vq_fixup(
    const float* __restrict__ x, const float* __restrict__ e,
    const int* __restrict__ fixCount, const unsigned int* __restrict__ fixList,
    float* __restrict__ outIdxF, float* __restrict__ outQ,
    float* __restrict__ bestDist, int* __restrict__ hist) {
  const int n = *fixCount;
  const int tid = threadIdx.x;
  __shared__ float xrow[256];
  __shared__ float rv[4];
  __shared__ int ri[4];
  __shared__ int sOld, sFi;
  for (int it = blockIdx.x; it < n; it += gridDim.x) {
    const unsigned e0 = fixList[it * 2];
    const int t = (int)(e0 & 0x3FFFFFFFu);
    const bool full = (e0 >> 31) != 0u;
    if (!full) {
      if (tid < 64) {
        const int i1 = (int)outIdxF[t];
        const int i2 = (int)fixList[it * 2 + 1];
        const float4 xv = reinterpret_cast<const float4*>(&x[t * DIM])[tid];
        const float4 e1 = reinterpret_cast<const float4*>(&e[i1 * DIM])[tid];
        const float4 e2 = reinterpret_cast<const float4*>(&e[i2 * DIM])[tid];
        float d1 = (xv.x - e1.x) * (xv.x - e1.x) + (xv.y - e1.y) * (xv.y - e1.y) +
                   (xv.z - e1.z) * (xv.z - e1.z) + (xv.w - e1.w) * (xv.w - e1.w);
        float d2 = (xv.x - e2.x) * (xv.x - e2.x) + (xv.y - e2.y) * (xv.y - e2.y) +
                   (xv.z - e2.z) * (xv.z - e2.z) + (xv.w - e2.w) * (xv.w - e2.w);
#pragma unroll
        for (int m = 32; m > 0; m >>= 1) {
          d1 += __shfl_xor(d1, m, 64);
          d2 += __shfl_xor(d2, m, 64);
        }
        const bool swap2 = (d2 < d1) || (d2 == d1 && i2 < i1);
        const int wIdx = swap2 ? i2 : i1;
        const float wD = swap2 ? d2 : d1;
        if (tid == 0) {
          bestDist[t] = wD;
          if (wIdx != i1) {
            atomicSub(&hist[i1], 1);
            atomicAdd(&hist[wIdx], 1);
            outIdxF[t] = (float)wIdx;
          }
        }
        if (swap2) {
          const float4 q = reinterpret_cast<const float4*>(&e[wIdx * DIM])[tid];
          reinterpret_cast<float4*>(&outQ[t * DIM])[tid] = q;
        }
      }
    } else {
      __syncthreads();
      if (tid < 64) ((float4*)xrow)[tid] = ((const float4*)&x[t * DIM])[tid];
      __syncthreads();
      float bv = 3.4e38f; int bi = 0;
      for (int c = tid; c < KC; c += 256) {
        float s = 0.f;
#pragma unroll
        for (int d = 0; d < DIM; d += 4) {
          const float4 ev = *(const float4*)&e[c * DIM + d];
          const float d0 = xrow[d] - ev.x, d1 = xrow[d + 1] - ev.y;
          const float d2 = xrow[d + 2] - ev.z, d3 = xrow[d + 3] - ev.w;
          s += d0 * d0 + d1 * d1 + d2 * d2 + d3 * d3;
        }
        if (s < bv) { bv = s; bi = c; }
      }
#pragma unroll
      for (int m = 1; m <= 32; m <<= 1) {
        const float ob = __shfl_xor(bv, m, 64);
        const int oi = __shfl_xor(bi, m, 64);
        if (ob < bv || (ob == bv && oi < bi)) { bv = ob; bi = oi; }
      }
      const int lane = tid & 63, wv = tid >> 6;
      if (lane == 0) { rv[wv] = bv; ri[wv] = bi; }
      __syncthreads();
      if (tid == 0) {
        float fb = rv[0]; int fi = ri[0];
        for (int k = 1; k < 4; ++k)
          if (rv[k] < fb || (rv[k] == fb && ri[k] < fi)) { fb = rv[k]; fi = ri[k]; }
        sOld = (int)outIdxF[t];
        sFi = fi;
        bestDist[t] = fb;
        if (fi != sOld) {
          atomicSub(&hist[sOld], 1);
          atomicAdd(&hist[fi], 1);
          outIdxF[t] = (float)fi;
        }
      }
      __syncthreads();
      if (sFi != sOld) outQ[t * DIM + tid] = e[sFi * DIM + tid];
      __syncthreads();
    }
  }
}

// ---- final scalars: loss = 0.25 * mean(bestDist); perplexity ----
__global__ __launch_bounds__(1024) void vq_final(
    const int* __restrict__ hist, const float* __restrict__ bestDist,
    float* __restrict__ outLoss, float* __restrict__ outPerp) {
  const int tid = threadIdx.x;
  float ls = 0.f;
  for (int i = 0; i < 64; ++i) ls += bestDist[tid + i * 1024];
  const float p = (float)hist[tid] * (1.f / 65536.f);
  float ent = p * logf(p + 1e-10f);
#pragma unroll
  for (int o = 32; o > 0; o >>= 1) {
    ls += __shfl_down(ls, o, 64);
    ent += __shfl_down(ent, o, 64);
  }
  __shared__ float lbuf[16], ebuf[16];
  const int lane = tid & 63, wv = tid >> 6;
  if (lane == 0) { lbuf[wv] = ls; ebuf[wv] = ent; }
  __syncthreads();
  if (tid == 0) {
    float L = 0.f, E = 0.f;
    for (int i = 0; i < 16; ++i) { L += lbuf[i]; E += ebuf[i]; }
    *outLoss = 0.25f * (L / 16777216.f);
    *outPerp = expf(-E);
  }
}

extern "C" void kernel_launch(void* const* d_in, const int* in_sizes, int n_in,
                              void* d_out, int out_size, void* d_ws, size_t ws_size,
                              hipStream_t stream) {
  const float* x = (const float*)d_in[0];  // [65536, 256]
  const float* e = (const float*)d_in[1];  // [1024, 256]
  float* out = (float*)d_out;
  float* outQ = out;                 // 16777216 floats
  float* outLoss = out + 16777216;
  float* outPerp = out + 16777217;
  float* outIdxF = out + 16777218;   // 65536 floats

  // scratch inside d_out's quantized region; records fully consumed by
  // vq_finish1 before vq_gather/vq_fixup write outQ (stream-ordered):
  unsigned short* xg = (unsigned short*)d_out;           // bytes [0, 32 MB)
  unsigned int* rK1 = (unsigned int*)(out + 8388608);    // [32, 40 MB)
  unsigned int* rK2 = (unsigned int*)(out + 10485760);   // [40, 48 MB)
  unsigned int* rK3 = (unsigned int*)(out + 12582912);   // [48, 56 MB)

  char* ws = (char*)d_ws;
  int*   hist     = (int*)ws;                     // 4 KB
  float* esq      = (float*)(ws + 4096);          // 4 KB
  float* xsq      = (float*)(ws + 8192);          // 256 KB
  float* bestDist = (float*)(ws + 270336);        // 256 KB
  int*   fixCount = (int*)(ws + 532480);          // 16 B
  unsigned int* fixList = (unsigned int*)(ws + 532496);  // 512 KB
  unsigned short* e_f16 = (unsigned short*)(ws + 1056784);  // 512 KB

  vq_prep_e<<<128, 256, 0, stream>>>(e, e_f16, esq, hist, fixCount);
  vq_prep_x<<<8192, 256, 0, stream>>>(x, xg, xsq);
  vq_argmin<<<2048, 256, 0, stream>>>(xg, e_f16, esq, rK1, rK2, rK3);
  vq_finish1<<<256, 256, 0, stream>>>(rK1, rK2, rK3, xsq, outIdxF, bestDist,
                                      hist, fixCount, fixList);
  vq_gather<<<1024, 256, 0, stream>>>(e, outIdxF, outQ);
  vq_fixup<<<256, 256, 0, stream>>>(x, e, fixCount, fixList, outIdxF, outQ,
                                    bestDist, hist);
  vq_final<<<1, 1024, 0, stream>>>(hist, bestDist, outLoss, outPerp);
}

// Round 20
// 172.731 us; speedup vs baseline: 1.5109x; 1.0329x over previous
//
#include <hip/hip_runtime.h>

#define NTOK 65536
#define DIM 256
#define KC 1024
#define EPS 0.08f

typedef __attribute__((ext_vector_type(8))) _Float16 f16x8;
typedef __attribute__((ext_vector_type(8))) unsigned short u16x8;
typedef __attribute__((ext_vector_type(4))) float f32x4;

static __device__ __forceinline__ unsigned short f16bits(float f) {
  _Float16 h = (_Float16)f;
  return __builtin_bit_cast(unsigned short, h);
}
// monotone pack: key orders like (dist, code); low 10 bits = code
static __device__ __forceinline__ unsigned packKey(float d, int code) {
  unsigned b = __float_as_uint(d);
  b = ((int)b < 0) ? ~b : (b | 0x80000000u);
  return (b & ~1023u) | (unsigned)code;
}
static __device__ __forceinline__ float decKey(unsigned k) {
  unsigned b = k & ~1023u;
  b = (b & 0x80000000u) ? (b ^ 0x80000000u) : ~b;
  return __uint_as_float(b);
}

// ---- fused prep: blocks [0,128) = e-prep; [128, 8320) = x-prep ----
__global__ __launch_bounds__(256) void vq_prep(
    const float* __restrict__ e, const float* __restrict__ x,
    unsigned short* __restrict__ eg, unsigned short* __restrict__ xg,
    float* __restrict__ esq, float* __restrict__ xsq,
    int* __restrict__ hist, int* __restrict__ fixCount) {
  if (blockIdx.x < 128) {
    const int gid = blockIdx.x * 256 + threadIdx.x;  // 32768 items
    const int t = gid >> 5;
    const int o = gid & 31;
    const float4 v0 = *reinterpret_cast<const float4*>(&e[t * DIM + o * 8]);
    const float4 v1 = *reinterpret_cast<const float4*>(&e[t * DIM + o * 8 + 4]);
    u16x8 u;
    u[0] = f16bits(v0.x); u[1] = f16bits(v0.y); u[2] = f16bits(v0.z); u[3] = f16bits(v0.w);
    u[4] = f16bits(v1.x); u[5] = f16bits(v1.y); u[6] = f16bits(v1.z); u[7] = f16bits(v1.w);
    const int ctk = t >> 6, njj = (t >> 4) & 3, col = t & 15;
    const int s = o >> 2, kq = o & 3;
    char* dst = (char*)eg + ((ctk * 32 + s * 4 + njj) << 10) + ((kq * 16 + col) << 4);
    *reinterpret_cast<u16x8*>(dst) = u;
    float p = v0.x * v0.x + v0.y * v0.y + v0.z * v0.z + v0.w * v0.w +
              v1.x * v1.x + v1.y * v1.y + v1.z * v1.z + v1.w * v1.w;
#pragma unroll
    for (int m = 16; m > 0; m >>= 1) p += __shfl_xor(p, m, 64);
    if (o == 0) esq[t] = p;
    if (blockIdx.x < 4) hist[blockIdx.x * 256 + threadIdx.x] = 0;
    if (gid == 0) *fixCount = 0;
  } else {
    const int gid = (blockIdx.x - 128) * 256 + threadIdx.x;  // 2097152 items
    const int t = gid >> 5;
    const int o = gid & 31;
    const float4 v0 = *reinterpret_cast<const float4*>(&x[t * DIM + o * 8]);
    const float4 v1 = *reinterpret_cast<const float4*>(&x[t * DIM + o * 8 + 4]);
    u16x8 u;
    u[0] = f16bits(v0.x); u[1] = f16bits(v0.y); u[2] = f16bits(v0.z); u[3] = f16bits(v0.w);
    u[4] = f16bits(v1.x); u[5] = f16bits(v1.y); u[6] = f16bits(v1.z); u[7] = f16bits(v1.w);
    const int s = o >> 2, kq = o & 3;
    char* dst = (char*)xg + (((t >> 4) * 8 + s) << 10) + ((kq * 16 + (t & 15)) << 4);
    *reinterpret_cast<u16x8*>(dst) = u;
    float p = v0.x * v0.x + v0.y * v0.y + v0.z * v0.z + v0.w * v0.w +
              v1.x * v1.x + v1.y * v1.y + v1.z * v1.z + v1.w * v1.w;
#pragma unroll
    for (int m = 16; m > 0; m >>= 1) p += __shfl_xor(p, m, 64);
    if (o == 0) xsq[t] = p;
  }
}

// ---- FLIPPED argmin: e in registers (asm loads), x streamed, XCD-pinned ----
__global__ __launch_bounds__(256, 4) void vq_argmin(
    const unsigned short* __restrict__ xg, const unsigned short* __restrict__ eg,
    const float* __restrict__ esq, unsigned int* __restrict__ rK1,
    unsigned int* __restrict__ rK2, unsigned int* __restrict__ rK3) {
  const int lane = threadIdx.x & 63, w = threadIdx.x >> 6;
  const int col = lane & 15, kq = lane >> 4;
  const int g = blockIdx.x & 7;        // XCD (dispatch round-robin)
  const int j = blockIdx.x >> 3;
  const int cp = j & 7;                // code partition
  const int tb = g * 32 + (j >> 3);    // token-block, XCD-local
  const int cbase = cp * 128 + w * 32;
  const int ctk = cbase >> 6;
  const int njb = (w & 1) * 2;
  const int pw = cp * 4 + w;           // wave-partition id

  // e-fragments: 16 asm loads (not rematerializable)
  f16x8 ae[8][2];
#pragma unroll
  for (int s = 0; s < 8; ++s)
#pragma unroll
    for (int cg = 0; cg < 2; ++cg) {
      const char* ap =
          (const char*)eg + ((ctk * 32 + s * 4 + njb + cg) << 10) + (lane << 4);
      asm volatile("global_load_dwordx4 %0, %1, off"
                   : "=v"(ae[s][cg]) : "v"(ap) : "memory");
    }
  float esr[2][4];
#pragma unroll
  for (int cg = 0; cg < 2; ++cg)
#pragma unroll
    for (int r = 0; r < 4; ++r)
      esr[cg][r] = esq[cbase + cg * 16 + kq * 4 + r];
  asm volatile("s_waitcnt vmcnt(0)" ::: "memory");
  __builtin_amdgcn_sched_barrier(0);

#pragma unroll 2
  for (int i = 0; i < 16; ++i) {
    const int tsub = tb * 16 + i;
    f32x4 acc[2];
    acc[0] = (f32x4){0.f, 0.f, 0.f, 0.f};
    acc[1] = (f32x4){0.f, 0.f, 0.f, 0.f};
#pragma unroll
    for (int s = 0; s < 8; ++s) {
      const f16x8 bx = *reinterpret_cast<const f16x8*>(
          (const char*)xg + ((tsub * 8 + s) << 10) + (lane << 4));
      acc[0] = __builtin_amdgcn_mfma_f32_16x16x32_f16(ae[s][0], bx, acc[0], 0, 0, 0);
      acc[1] = __builtin_amdgcn_mfma_f32_16x16x32_f16(ae[s][1], bx, acc[1], 0, 0, 0);
    }
    // per lane: token = tsub*16 + col; 8 codes -> packed top-3
    unsigned k1 = 0xFFFFFFFFu, k2 = 0xFFFFFFFFu, k3 = 0xFFFFFFFFu;
#pragma unroll
    for (int cg = 0; cg < 2; ++cg)
#pragma unroll
      for (int r = 0; r < 4; ++r) {
        const int code = cbase + cg * 16 + kq * 4 + r;
        const unsigned k = packKey(fmaf(-2.f, acc[cg][r], esr[cg][r]), code);
        if (k < k1) { k3 = k2; k2 = k1; k1 = k; }
        else if (k < k2) { k3 = k2; k2 = k; }
        else if (k < k3) { k3 = k; }
      }
    // cross-kq merge (masks 16, 32): sorted-triple merge network
#pragma unroll
    for (int m = 16; m <= 32; m <<= 1) {
      const unsigned o1 = __shfl_xor((int)k1, m, 64);
      const unsigned o2 = __shfl_xor((int)k2, m, 64);
      const unsigned o3 = __shfl_xor((int)k3, m, 64);
      const unsigned t1 = max(k1, o1), lo2 = min(k2, o2);
      const unsigned nm1 = min(k1, o1);
      const unsigned nm2 = min(t1, lo2);
      const unsigned nm3 = min(min(max(t1, lo2), max(k2, o2)), min(k3, o3));
      k1 = nm1; k2 = nm2; k3 = nm3;
    }
    if (kq == 0) {  // lanes 0..15: one 12-B record per (wave-partition, token)
      const int rb = pw * NTOK + tsub * 16 + col;
      rK1[rb] = k1; rK2[rb] = k2; rK3[rb] = k3;
    }
  }
}

// ---- merge 32 wave-partition packed triples -> idx/bestDist/hist/fix ----
__global__ __launch_bounds__(256) void vq_finish1(
    const unsigned int* __restrict__ rK1, const unsigned int* __restrict__ rK2,
    const unsigned int* __restrict__ rK3, const float* __restrict__ xsq,
    float* __restrict__ outIdxF, float* __restrict__ bestDist,
    int* __restrict__ hist, int* __restrict__ fixCount,
    unsigned int* __restrict__ fixList) {
  const int t = blockIdx.x * 256 + threadIdx.x;
  unsigned m1 = 0xFFFFFFFFu, m2 = 0xFFFFFFFFu, m3 = 0xFFFFFFFFu;
  unsigned minFlagK1 = 0xFFFFFFFFu;
#pragma unroll
  for (int p = 0; p < 32; ++p) {
    const int rb = p * NTOK + t;
    const unsigned a1 = rK1[rb], a2 = rK2[rb], a3 = rK3[rb];
    if (decKey(a3) - decKey(a1) < EPS) minFlagK1 = min(minFlagK1, a1);
    const unsigned t1 = max(m1, a1), lo2 = min(m2, a2);
    const unsigned nm1 = min(m1, a1);
    const unsigned nm2 = min(t1, lo2);
    const unsigned nm3 = min(min(max(t1, lo2), max(m2, a2)), min(m3, a3));
    m1 = nm1; m2 = nm2; m3 = nm3;
  }
  const int mi1 = (int)(m1 & 1023u);
  const float d1 = decKey(m1);
  outIdxF[t] = (float)mi1;
  bestDist[t] = xsq[t] + d1;
  atomicAdd(&hist[mi1], 1);
  if (decKey(m2) - d1 < EPS) {
    const bool full = (decKey(m3) - d1 < EPS) || (decKey(minFlagK1) - d1 < EPS);
    const int p = atomicAdd(fixCount, 1);
    fixList[p * 2] = (unsigned)t | (full ? 0x80000000u : 0u);
    fixList[p * 2 + 1] = m2 & 1023u;
  }
}

// ---- fixup (BEFORE gather): patches idx/hist/bestDist only ----
__global__ __launch_bounds__(256) void vq_fixup(
    const float* __restrict__ x, const float* __restrict__ e,
    const int* __restrict__ fixCount, const unsigned int* __restrict__ fixList,
    float* __restrict__ outIdxF, float* __restrict__ bestDist,
    int* __restrict__ hist) {
  const int n = *fixCount;
  const int tid = threadIdx.x;
  __shared__ float xrow[256];
  __shared__ float rv[4];
  __shared__ int ri[4];
  for (int it = blockIdx.x; it < n; it += gridDim.x) {
    const unsigned e0 = fixList[it * 2];
    const int t = (int)(e0 & 0x3FFFFFFFu);
    const bool full = (e0 >> 31) != 0u;
    if (!full) {
      if (tid < 64) {
        const int i1 = (int)outIdxF[t];
        const int i2 = (int)fixList[it * 2 + 1];
        const float4 xv = reinterpret_cast<const float4*>(&x[t * DIM])[tid];
        const float4 e1 = reinterpret_cast<const float4*>(&e[i1 * DIM])[tid];
        const float4 e2 = reinterpret_cast<const float4*>(&e[i2 * DIM])[tid];
        float d1 = (xv.x - e1.x) * (xv.x - e1.x) + (xv.y - e1.y) * (xv.y - e1.y) +
                   (xv.z - e1.z) * (xv.z - e1.z) + (xv.w - e1.w) * (xv.w - e1.w);
        float d2 = (xv.x - e2.x) * (xv.x - e2.x) + (xv.y - e2.y) * (xv.y - e2.y) +
                   (xv.z - e2.z) * (xv.z - e2.z) + (xv.w - e2.w) * (xv.w - e2.w);
#pragma unroll
        for (int m = 32; m > 0; m >>= 1) {
          d1 += __shfl_xor(d1, m, 64);
          d2 += __shfl_xor(d2, m, 64);
        }
        const bool swap2 = (d2 < d1) || (d2 == d1 && i2 < i1);
        if (tid == 0) {
          bestDist[t] = swap2 ? d2 : d1;
          if (swap2) {
            atomicSub(&hist[i1], 1);
            atomicAdd(&hist[i2], 1);
            outIdxF[t] = (float)i2;
          }
        }
      }
    } else {
      __syncthreads();
      if (tid < 64) ((float4*)xrow)[tid] = ((const float4*)&x[t * DIM])[tid];
      __syncthreads();
      float bv = 3.4e38f; int bi = 0;
      for (int c = tid; c < KC; c += 256) {
        float s = 0.f;
#pragma unroll
        for (int d = 0; d < DIM; d += 4) {
          const float4 ev = *(const float4*)&e[c * DIM + d];
          const float d0 = xrow[d] - ev.x, d1 = xrow[d + 1] - ev.y;
          const float d2 = xrow[d + 2] - ev.z, d3 = xrow[d + 3] - ev.w;
          s += d0 * d0 + d1 * d1 + d2 * d2 + d3 * d3;
        }
        if (s < bv) { bv = s; bi = c; }
      }
#pragma unroll
      for (int m = 1; m <= 32; m <<= 1) {
        const float ob = __shfl_xor(bv, m, 64);
        const int oi = __shfl_xor(bi, m, 64);
        if (ob < bv || (ob == bv && oi < bi)) { bv = ob; bi = oi; }
      }
      const int lane = tid & 63, wv = tid >> 6;
      if (lane == 0) { rv[wv] = bv; ri[wv] = bi; }
      __syncthreads();
      if (tid == 0) {
        float fb = rv[0]; int fi = ri[0];
        for (int k = 1; k < 4; ++k)
          if (rv[k] < fb || (rv[k] == fb && ri[k] < fi)) { fb = rv[k]; fi = ri[k]; }
        const int sOld = (int)outIdxF[t];
        bestDist[t] = fb;
        if (fi != sOld) {
          atomicSub(&hist[sOld], 1);
          atomicAdd(&hist[fi], 1);
          outIdxF[t] = (float)fi;
        }
      }
      __syncthreads();
    }
  }
}

// ---- gather (AFTER fixup): final outIdxF -> outQ, single writer ----
__global__ __launch_bounds__(256) void vq_gather(
    const float* __restrict__ e, const float* __restrict__ outIdxF,
    float* __restrict__ outQ) {
  const int lane = threadIdx.x & 63, w = threadIdx.x >> 6;
  const int t0 = blockIdx.x * 64 + w * 16;
#pragma unroll
  for (int i = 0; i < 16; ++i) {
    const int t = t0 + i;
    const int id = (int)outIdxF[t];
    const float4 q = reinterpret_cast<const float4*>(&e[id * DIM])[lane];
    reinterpret_cast<float4*>(&outQ[t * DIM])[lane] = q;
  }
}

// ---- final scalars: loss = 0.25 * mean(bestDist); perplexity ----
__global__ __launch_bounds__(1024) void vq_final(
    const int* __restrict__ hist, const float* __restrict__ bestDist,
    float* __restrict__ outLoss, float* __restrict__ outPerp) {
  const int tid = threadIdx.x;
  float ls = 0.f;
  for (int i = 0; i < 64; ++i) ls += bestDist[tid + i * 1024];
  const float p = (float)hist[tid] * (1.f / 65536.f);
  float ent = p * logf(p + 1e-10f);
#pragma unroll
  for (int o = 32; o > 0; o >>= 1) {
    ls += __shfl_down(ls, o, 64);
    ent += __shfl_down(ent, o, 64);
  }
  __shared__ float lbuf[16], ebuf[16];
  const int lane = tid & 63, wv = tid >> 6;
  if (lane == 0) { lbuf[wv] = ls; ebuf[wv] = ent; }
  __syncthreads();
  if (tid == 0) {
    float L = 0.f, E = 0.f;
    for (int i = 0; i < 16; ++i) { L += lbuf[i]; E += ebuf[i]; }
    *outLoss = 0.25f * (L / 16777216.f);
    *outPerp = expf(-E);
  }
}

extern "C" void kernel_launch(void* const* d_in, const int* in_sizes, int n_in,
                              void* d_out, int out_size, void* d_ws, size_t ws_size,
                              hipStream_t stream) {
  const float* x = (const float*)d_in[0];  // [65536, 256]
  const float* e = (const float*)d_in[1];  // [1024, 256]
  float* out = (float*)d_out;
  float* outQ = out;                 // 16777216 floats
  float* outLoss = out + 16777216;
  float* outPerp = out + 16777217;
  float* outIdxF = out + 16777218;   // 65536 floats

  // scratch inside d_out's quantized region; records consumed by vq_finish1,
  // xg consumed by vq_argmin — both before vq_gather writes outQ (stream
  // order: finish1 -> fixup -> gather).
  unsigned short* xg = (unsigned short*)d_out;           // bytes [0, 32 MB)
  unsigned int* rK1 = (unsigned int*)(out + 8388608);    // [32, 40 MB)
  unsigned int* rK2 = (unsigned int*)(out + 10485760);   // [40, 48 MB)
  unsigned int* rK3 = (unsigned int*)(out + 12582912);   // [48, 56 MB)

  char* ws = (char*)d_ws;
  int*   hist     = (int*)ws;                     // 4 KB
  float* esq      = (float*)(ws + 4096);          // 4 KB
  float* xsq      = (float*)(ws + 8192);          // 256 KB
  float* bestDist = (float*)(ws + 270336);        // 256 KB
  int*   fixCount = (int*)(ws + 532480);          // 16 B
  unsigned int* fixList = (unsigned int*)(ws + 532496);  // 512 KB
  unsigned short* e_f16 = (unsigned short*)(ws + 1056784);  // 512 KB

  vq_prep<<<8320, 256, 0, stream>>>(e, x, e_f16, xg, esq, xsq, hist, fixCount);
  vq_argmin<<<2048, 256, 0, stream>>>(xg, e_f16, esq, rK1, rK2, rK3);
  vq_finish1<<<256, 256, 0, stream>>>(rK1, rK2, rK3, xsq, outIdxF, bestDist,
                                      hist, fixCount, fixList);
  vq_fixup<<<256, 256, 0, stream>>>(x, e, fixCount, fixList, outIdxF,
                                    bestDist, hist);
  vq_gather<<<1024, 256, 0, stream>>>(e, outIdxF, outQ);
  vq_final<<<1, 1024, 0, stream>>>(hist, bestDist, outLoss, outPerp);
}

// Round 21
// 167.040 us; speedup vs baseline: 1.5624x; 1.0341x over previous
//
#include <hip/hip_runtime.h>

#define NTOK 65536
#define DIM 256
#define KC 1024
#define EPS 0.08f

typedef __attribute__((ext_vector_type(8))) _Float16 f16x8;
typedef __attribute__((ext_vector_type(8))) unsigned short u16x8;
typedef __attribute__((ext_vector_type(4))) float f32x4;

static __device__ __forceinline__ unsigned short f16bits(float f) {
  _Float16 h = (_Float16)f;
  return __builtin_bit_cast(unsigned short, h);
}
// branchless monotone pack: orders like (dist, code); low 10 bits = code
static __device__ __forceinline__ unsigned packKey(float d, int code) {
  unsigned b = __float_as_uint(d);
  b ^= (unsigned)((int)b >> 31) | 0x80000000u;
  return (b & ~1023u) | (unsigned)code;
}
static __device__ __forceinline__ float decKey(unsigned k) {
  unsigned b = k & ~1023u;
  b = (b & 0x80000000u) ? (b ^ 0x80000000u) : ~b;
  return __uint_as_float(b);
}

// ---- unified prep: fp32 -> f16 panel image (chunk = (row>>4)*8+s) ----
// blocks [0,1024): x (64 tokens each); [1024,1040): e (64 codes each).
// LDS transpose: coalesced row reads -> contiguous 1-KB chunk writes.
__global__ __launch_bounds__(256) void vq_prep(
    const float* __restrict__ x, const float* __restrict__ e,
    unsigned short* __restrict__ xg, unsigned short* __restrict__ eg,
    float* __restrict__ xsq, float* __restrict__ esq,
    int* __restrict__ hist, int* __restrict__ fixCount) {
  __shared__ char lds[32768];  // 32 chunks x 1 KB
  const int tid = threadIdx.x;
  const bool isE = blockIdx.x >= 1024;
  const int rb = isE ? (int)blockIdx.x - 1024 : (int)blockIdx.x;
  const float* src = isE ? e : x;
  unsigned short* img = isE ? eg : xg;
  float* sq = isE ? esq : xsq;

  const int tk = tid >> 2;   // local row 0..63
  const int part = tid & 3;  // k-quarter (64 floats)
  const int row = rb * 64 + tk;
  const float4* srow =
      reinterpret_cast<const float4*>(&src[row * DIM]) + part * 16;
  float s = 0.f;
#pragma unroll
  for (int o = 0; o < 8; ++o) {  // octets within this quarter
    const float4 v0 = srow[o * 2];
    const float4 v1 = srow[o * 2 + 1];
    u16x8 u;
    u[0] = f16bits(v0.x); u[1] = f16bits(v0.y);
    u[2] = f16bits(v0.z); u[3] = f16bits(v0.w);
    u[4] = f16bits(v1.x); u[5] = f16bits(v1.y);
    u[6] = f16bits(v1.z); u[7] = f16bits(v1.w);
    const int oo = part * 8 + o;  // global octet 0..31
    char* d = lds + ((tk >> 4) * 8 + (oo >> 2)) * 1024 +
              (((oo & 3) * 16 + (tk & 15)) << 4);
    *reinterpret_cast<u16x8*>(d) = u;
    s += v0.x * v0.x + v0.y * v0.y + v0.z * v0.z + v0.w * v0.w +
         v1.x * v1.x + v1.y * v1.y + v1.z * v1.z + v1.w * v1.w;
  }
  s += __shfl_xor(s, 1, 64);
  s += __shfl_xor(s, 2, 64);
  if (part == 0) sq[row] = s;
  __syncthreads();
  const int w = tid >> 6, lane = tid & 63;
#pragma unroll
  for (int r = 0; r < 8; ++r) {  // 32 contiguous 1-KB chunk writes
    const int c = r * 4 + w;
    *reinterpret_cast<u16x8*>((char*)img + (rb * 32 + c) * 1024 + lane * 16) =
        *reinterpret_cast<const u16x8*>(lds + c * 1024 + lane * 16);
  }
  if (isE) {
    if (blockIdx.x < 1028) hist[(blockIdx.x - 1024) * 256 + tid] = 0;
    if (blockIdx.x == 1024 && tid == 0) *fixCount = 0;
  }
}

// ---- FLIPPED argmin: e in registers (asm loads), x streamed, XCD-pinned ----
__global__ __launch_bounds__(256, 4) void vq_argmin(
    const unsigned short* __restrict__ xg, const unsigned short* __restrict__ eg,
    const float* __restrict__ esq, unsigned int* __restrict__ rK1,
    unsigned int* __restrict__ rK2, unsigned int* __restrict__ rK3) {
  const int lane = threadIdx.x & 63, w = threadIdx.x >> 6;
  const int col = lane & 15, kq = lane >> 4;
  const int g = blockIdx.x & 7;        // XCD (dispatch round-robin)
  const int j = blockIdx.x >> 3;
  const int cp = j & 7;                // code partition
  const int tb = g * 32 + (j >> 3);    // token-block, XCD-local
  const int cbase = cp * 128 + w * 32;
  const int pw = cp * 4 + w;           // wave-partition id

  // e-fragments: 16 asm loads (unified panel layout)
  f16x8 ae[8][2];
#pragma unroll
  for (int s = 0; s < 8; ++s)
#pragma unroll
    for (int cg = 0; cg < 2; ++cg) {
      const char* ap = (const char*)eg +
                       (((cp * 8 + w * 2 + cg) * 8 + s) << 10) + (lane << 4);
      asm volatile("global_load_dwordx4 %0, %1, off"
                   : "=v"(ae[s][cg]) : "v"(ap) : "memory");
    }
  float esr[2][4];
#pragma unroll
  for (int cg = 0; cg < 2; ++cg)
#pragma unroll
    for (int r = 0; r < 4; ++r)
      esr[cg][r] = esq[cbase + cg * 16 + kq * 4 + r];
  asm volatile("s_waitcnt vmcnt(0)" ::: "memory");
  __builtin_amdgcn_sched_barrier(0);

#pragma unroll 2
  for (int i = 0; i < 16; ++i) {
    const int tsub = tb * 16 + i;
    f32x4 acc[2];
    acc[0] = (f32x4){0.f, 0.f, 0.f, 0.f};
    acc[1] = (f32x4){0.f, 0.f, 0.f, 0.f};
#pragma unroll
    for (int s = 0; s < 8; ++s) {
      const f16x8 bx = *reinterpret_cast<const f16x8*>(
          (const char*)xg + ((tsub * 8 + s) << 10) + (lane << 4));
      acc[0] = __builtin_amdgcn_mfma_f32_16x16x32_f16(ae[s][0], bx, acc[0], 0, 0, 0);
      acc[1] = __builtin_amdgcn_mfma_f32_16x16x32_f16(ae[s][1], bx, acc[1], 0, 0, 0);
    }
    // per lane: token = tsub*16 + col; 8 codes -> branchless packed top-3
    unsigned k1 = 0xFFFFFFFFu, k2 = 0xFFFFFFFFu, k3 = 0xFFFFFFFFu;
#pragma unroll
    for (int cg = 0; cg < 2; ++cg)
#pragma unroll
      for (int r = 0; r < 4; ++r) {
        const int code = cbase + cg * 16 + kq * 4 + r;
        const unsigned k = packKey(fmaf(-2.f, acc[cg][r], esr[cg][r]), code);
        const unsigned mx1 = max(k1, k); k1 = min(k1, k);
        const unsigned mx2 = max(k2, mx1); k2 = min(k2, mx1);
        k3 = min(k3, mx2);
      }
    // cross-kq merge (masks 16, 32): sorted-triple merge network
#pragma unroll
    for (int m = 16; m <= 32; m <<= 1) {
      const unsigned o1 = __shfl_xor((int)k1, m, 64);
      const unsigned o2 = __shfl_xor((int)k2, m, 64);
      const unsigned o3 = __shfl_xor((int)k3, m, 64);
      const unsigned t1 = max(k1, o1), lo2 = min(k2, o2);
      const unsigned nm1 = min(k1, o1);
      const unsigned nm2 = min(t1, lo2);
      const unsigned nm3 = min(min(max(t1, lo2), max(k2, o2)), min(k3, o3));
      k1 = nm1; k2 = nm2; k3 = nm3;
    }
    if (kq == 0) {  // lanes 0..15: one 12-B record per (wave-partition, token)
      const int rb2 = pw * NTOK + tsub * 16 + col;
      rK1[rb2] = k1; rK2[rb2] = k2; rK3[rb2] = k3;
    }
  }
}

// ---- merge 32 wave-partition packed triples -> idx/bestDist/hist/fix ----
__global__ __launch_bounds__(256) void vq_finish1(
    const unsigned int* __restrict__ rK1, const unsigned int* __restrict__ rK2,
    const unsigned int* __restrict__ rK3, const float* __restrict__ xsq,
    float* __restrict__ outIdxF, float* __restrict__ bestDist,
    int* __restrict__ hist, int* __restrict__ fixCount,
    unsigned int* __restrict__ fixList) {
  const int t = blockIdx.x * 256 + threadIdx.x;
  unsigned m1 = 0xFFFFFFFFu, m2 = 0xFFFFFFFFu, m3 = 0xFFFFFFFFu;
  unsigned minFlagK1 = 0xFFFFFFFFu;
#pragma unroll
  for (int p = 0; p < 32; ++p) {
    const int rb = p * NTOK + t;
    const unsigned a1 = rK1[rb], a2 = rK2[rb], a3 = rK3[rb];
    if (decKey(a3) - decKey(a1) < EPS) minFlagK1 = min(minFlagK1, a1);
    const unsigned t1 = max(m1, a1), lo2 = min(m2, a2);
    const unsigned nm1 = min(m1, a1);
    const unsigned nm2 = min(t1, lo2);
    const unsigned nm3 = min(min(max(t1, lo2), max(m2, a2)), min(m3, a3));
    m1 = nm1; m2 = nm2; m3 = nm3;
  }
  const int mi1 = (int)(m1 & 1023u);
  const float d1 = decKey(m1);
  outIdxF[t] = (float)mi1;
  bestDist[t] = xsq[t] + d1;
  atomicAdd(&hist[mi1], 1);
  if (decKey(m2) - d1 < EPS) {
    const bool full = (decKey(m3) - d1 < EPS) || (decKey(minFlagK1) - d1 < EPS);
    const int p = atomicAdd(fixCount, 1);
    fixList[p * 2] = (unsigned)t | (full ? 0x80000000u : 0u);
    fixList[p * 2 + 1] = m2 & 1023u;
  }
}

// ---- fixup (before gather): patches idx/hist/bestDist only ----
__global__ __launch_bounds__(256) void vq_fixup(
    const float* __restrict__ x, const float* __restrict__ e,
    const int* __restrict__ fixCount, const unsigned int* __restrict__ fixList,
    float* __restrict__ outIdxF, float* __restrict__ bestDist,
    int* __restrict__ hist) {
  const int n = *fixCount;
  const int tid = threadIdx.x;
  __shared__ float xrow[256];
  __shared__ float rv[4];
  __shared__ int ri[4];
  for (int it = blockIdx.x; it < n; it += gridDim.x) {
    const unsigned e0 = fixList[it * 2];
    const int t = (int)(e0 & 0x3FFFFFFFu);
    const bool full = (e0 >> 31) != 0u;
    if (!full) {
      if (tid < 64) {
        const int i1 = (int)outIdxF[t];
        const int i2 = (int)fixList[it * 2 + 1];
        const float4 xv = reinterpret_cast<const float4*>(&x[t * DIM])[tid];
        const float4 e1 = reinterpret_cast<const float4*>(&e[i1 * DIM])[tid];
        const float4 e2 = reinterpret_cast<const float4*>(&e[i2 * DIM])[tid];
        float d1 = (xv.x - e1.x) * (xv.x - e1.x) + (xv.y - e1.y) * (xv.y - e1.y) +
                   (xv.z - e1.z) * (xv.z - e1.z) + (xv.w - e1.w) * (xv.w - e1.w);
        float d2 = (xv.x - e2.x) * (xv.x - e2.x) + (xv.y - e2.y) * (xv.y - e2.y) +
                   (xv.z - e2.z) * (xv.z - e2.z) + (xv.w - e2.w) * (xv.w - e2.w);
#pragma unroll
        for (int m = 32; m > 0; m >>= 1) {
          d1 += __shfl_xor(d1, m, 64);
          d2 += __shfl_xor(d2, m, 64);
        }
        const bool swap2 = (d2 < d1) || (d2 == d1 && i2 < i1);
        if (tid == 0) {
          bestDist[t] = swap2 ? d2 : d1;
          if (swap2) {
            atomicSub(&hist[i1], 1);
            atomicAdd(&hist[i2], 1);
            outIdxF[t] = (float)i2;
          }
        }
      }
    } else {
      __syncthreads();
      if (tid < 64) ((float4*)xrow)[tid] = ((const float4*)&x[t * DIM])[tid];
      __syncthreads();
      float bv = 3.4e38f; int bi = 0;
      for (int c = tid; c < KC; c += 256) {
        float s = 0.f;
#pragma unroll
        for (int d = 0; d < DIM; d += 4) {
          const float4 ev = *(const float4*)&e[c * DIM + d];
          const float d0 = xrow[d] - ev.x, d1 = xrow[d + 1] - ev.y;
          const float d2 = xrow[d + 2] - ev.z, d3 = xrow[d + 3] - ev.w;
          s += d0 * d0 + d1 * d1 + d2 * d2 + d3 * d3;
        }
        if (s < bv) { bv = s; bi = c; }
      }
#pragma unroll
      for (int m = 1; m <= 32; m <<= 1) {
        const float ob = __shfl_xor(bv, m, 64);
        const int oi = __shfl_xor(bi, m, 64);
        if (ob < bv || (ob == bv && oi < bi)) { bv = ob; bi = oi; }
      }
      const int lane = tid & 63, wv = tid >> 6;
      if (lane == 0) { rv[wv] = bv; ri[wv] = bi; }
      __syncthreads();
      if (tid == 0) {
        float fb = rv[0]; int fi = ri[0];
        for (int k = 1; k < 4; ++k)
          if (rv[k] < fb || (rv[k] == fb && ri[k] < fi)) { fb = rv[k]; fi = ri[k]; }
        const int sOld = (int)outIdxF[t];
        bestDist[t] = fb;
        if (fi != sOld) {
          atomicSub(&hist[sOld], 1);
          atomicAdd(&hist[fi], 1);
          outIdxF[t] = (float)fi;
        }
      }
      __syncthreads();
    }
  }
}

// ---- fused tail: blocks [0,1024) gather outQ; block 1024 final scalars ----
__global__ __launch_bounds__(256) void vq_tail(
    const float* __restrict__ e, const float* __restrict__ outIdxF,
    const float* __restrict__ bestDist, const int* __restrict__ hist,
    float* __restrict__ outQ, float* __restrict__ outLoss,
    float* __restrict__ outPerp) {
  const int tid = threadIdx.x;
  if (blockIdx.x < 1024) {
    const int lane = tid & 63, w = tid >> 6;
    const int t0 = blockIdx.x * 64 + w * 16;
#pragma unroll
    for (int i = 0; i < 16; ++i) {
      const int t = t0 + i;
      const int id = (int)outIdxF[t];
      const float4 q = reinterpret_cast<const float4*>(&e[id * DIM])[lane];
      reinterpret_cast<float4*>(&outQ[t * DIM])[lane] = q;
    }
  } else {
    float ls = 0.f;
    const float4* bd4 = reinterpret_cast<const float4*>(bestDist);
    for (int i = 0; i < 64; ++i) {
      const float4 v = bd4[tid + i * 256];
      ls += v.x + v.y + v.z + v.w;
    }
    const int4 h4 = reinterpret_cast<const int4*>(hist)[tid];
    float ent = 0.f;
    {
      const float p0 = (float)h4.x * (1.f / 65536.f);
      const float p1 = (float)h4.y * (1.f / 65536.f);
      const float p2 = (float)h4.z * (1.f / 65536.f);
      const float p3 = (float)h4.w * (1.f / 65536.f);
      ent = p0 * logf(p0 + 1e-10f) + p1 * logf(p1 + 1e-10f) +
            p2 * logf(p2 + 1e-10f) + p3 * logf(p3 + 1e-10f);
    }
#pragma unroll
    for (int o = 32; o > 0; o >>= 1) {
      ls += __shfl_down(ls, o, 64);
      ent += __shfl_down(ent, o, 64);
    }
    __shared__ float lbuf[4], ebuf[4];
    const int lane = tid & 63, wv = tid >> 6;
    if (lane == 0) { lbuf[wv] = ls; ebuf[wv] = ent; }
    __syncthreads();
    if (tid == 0) {
      float L = 0.f, E = 0.f;
      for (int i = 0; i < 4; ++i) { L += lbuf[i]; E += ebuf[i]; }
      *outLoss = 0.25f * (L / 16777216.f);
      *outPerp = expf(-E);
    }
  }
}

extern "C" void kernel_launch(void* const* d_in, const int* in_sizes, int n_in,
                              void* d_out, int out_size, void* d_ws, size_t ws_size,
                              hipStream_t stream) {
  const float* x = (const float*)d_in[0];  // [65536, 256]
  const float* e = (const float*)d_in[1];  // [1024, 256]
  float* out = (float*)d_out;
  float* outQ = out;                 // 16777216 floats
  float* outLoss = out + 16777216;
  float* outPerp = out + 16777217;
  float* outIdxF = out + 16777218;   // 65536 floats

  // scratch inside d_out's quantized region; xg consumed by vq_argmin,
  // records by vq_finish1 — both before vq_tail writes outQ.
  unsigned short* xg = (unsigned short*)d_out;           // bytes [0, 32 MB)
  unsigned int* rK1 = (unsigned int*)(out + 8388608);    // [32, 40 MB)
  unsigned int* rK2 = (unsigned int*)(out + 10485760);   // [40, 48 MB)
  unsigned int* rK3 = (unsigned int*)(out + 12582912);   // [48, 56 MB)

  char* ws = (char*)d_ws;
  int*   hist     = (int*)ws;                     // 4 KB
  float* esq      = (float*)(ws + 4096);          // 4 KB
  float* xsq      = (float*)(ws + 8192);          // 256 KB
  float* bestDist = (float*)(ws + 270336);        // 256 KB
  int*   fixCount = (int*)(ws + 532480);          // 16 B
  unsigned int* fixList = (unsigned int*)(ws + 532496);  // 512 KB
  unsigned short* e_f16 = (unsigned short*)(ws + 1056784);  // 512 KB

  vq_prep<<<1040, 256, 0, stream>>>(x, e, xg, e_f16, xsq, esq, hist, fixCount);
  vq_argmin<<<2048, 256, 0, stream>>>(xg, e_f16, esq, rK1, rK2, rK3);
  vq_finish1<<<256, 256, 0, stream>>>(rK1, rK2, rK3, xsq, outIdxF, bestDist,
                                      hist, fixCount, fixList);
  vq_fixup<<<256, 256, 0, stream>>>(x, e, fixCount, fixList, outIdxF,
                                    bestDist, hist);
  vq_tail<<<1025, 256, 0, stream>>>(e, outIdxF, bestDist, hist, outQ,
                                    outLoss, outPerp);
}